// Round 1
// baseline (11469.791 us; speedup 1.0000x reference)
//
#include <hip/hip_runtime.h>

// S2VT + attention, decomposed:
//  1. cvt fp32->bf16 (video, enc_Wih, attn_W, dec_Wih, fc_W)
//  2. K1 GEMM: X_gates[b*80+t, 2048] = video @ enc_Wih^T + bih + bhh   (bf16 MFMA)
//  3. k_enc persistent: 80 LSTM steps, grid barrier per step; writes enc_out (f32+bf16), final h,c
//  4. EncPart GEMM: enc_out @ attn_W[:,512:]^T + attn_b
//     E_gates GEMM: emb[tok] @ dec_Wih[:,:512]^T + dbih + dbhh
//  5. k_dec persistent: 30 steps x {hW, attention+softmax+ctx, gates+LSTM}; writes Hs bf16
//  6. FC GEMM: Hs @ fc_W^T + fc_b -> out[b][l][v]   (bf16 MFMA)

#define DEV __device__ __forceinline__

typedef __attribute__((ext_vector_type(4))) float f32x4;
typedef __attribute__((ext_vector_type(8))) short bf16x8;

static constexpr int B_ = 64, T_ = 80, H_ = 512, L_ = 31, NDEC = 30;

DEV unsigned short f2bf(float f) {
  unsigned u = __builtin_bit_cast(unsigned, f);
  u += 0x7FFF + ((u >> 16) & 1);
  return (unsigned short)(u >> 16);
}
DEV float sigmoidf(float x) { return 1.f / (1.f + __expf(-x)); }
DEV float tanh_fast(float x) { float e = __expf(2.f * x); return (e - 1.f) / (e + 1.f); }

// ---------------- fp32 -> bf16 convert ----------------
__global__ __launch_bounds__(256) void k_cvt(const float* __restrict__ in,
                                             unsigned short* __restrict__ out, long n4) {
  long i = (long)blockIdx.x * 256 + threadIdx.x;
  long stride = (long)gridDim.x * 256;
  for (; i < n4; i += stride) {
    float4 v = reinterpret_cast<const float4*>(in)[i];
    ushort4 o;
    o.x = f2bf(v.x); o.y = f2bf(v.y); o.z = f2bf(v.z); o.w = f2bf(v.w);
    reinterpret_cast<ushort4*>(out)[i] = o;
  }
}

// ---------------- int64-vs-int32 caption detect ----------------
__global__ void k_detect_i64(const int* __restrict__ cap, int* __restrict__ flag) {
  __shared__ int s;
  if (threadIdx.x == 0) s = 0;
  __syncthreads();
  int acc = 0;
  for (int i = threadIdx.x; i < (B_ * L_) / 2; i += 256) acc |= cap[2 * i + 1];
  if (acc) atomicOr(&s, 1);
  __syncthreads();
  if (threadIdx.x == 0) flag[0] = (s == 0) ? 1 : 0;  // all-high-words-zero => int64
}

// ---------------- embedding gather (rows r = l*64+b) ----------------
__global__ __launch_bounds__(256) void k_gather_emb(const float* __restrict__ emb,
                                                    const int* __restrict__ cap,
                                                    const int* __restrict__ flag,
                                                    unsigned short* __restrict__ aemb) {
  int r = blockIdx.x;            // 0..1919
  int l = r >> 6, b = r & 63;
  int ci = b * L_ + l;
  int tok = flag[0] ? cap[2 * ci] : cap[ci];
  const float* src = emb + (size_t)tok * H_;
  unsigned short* dst = aemb + (size_t)r * H_;
  for (int c = threadIdx.x; c < H_; c += 256) dst[c] = f2bf(src[c]);
}

// ---------------- bf16 MFMA GEMM: C[M,N] = A[M,K] * B[N,K]^T + bias ----------------
// 128x128 tile, BK=32, 4 waves (each 64x64 = 4x4 fragments of 16x16x32).
// LDS row pitch 40 shorts (80B) to break the 64B-stride bank conflict.
template <int OUT_MODE>  // 0: row-major ldc=N ; 1: row r=(l*64+b) -> out[(b*30+l)*N + col]
__global__ __launch_bounds__(256) void k_gemm(const unsigned short* __restrict__ A, int lda,
                                              const unsigned short* __restrict__ Bm, int ldb,
                                              float* __restrict__ C, int N, int K,
                                              const float* __restrict__ bias0,
                                              const float* __restrict__ bias1) {
  __shared__ __align__(16) unsigned short As[128 * 40];
  __shared__ __align__(16) unsigned short Bs[128 * 40];
  const int tid = threadIdx.x;
  const int m0 = blockIdx.y * 128, n0 = blockIdx.x * 128;
  const int wave = tid >> 6, lane = tid & 63;
  const int wm = wave >> 1, wn = wave & 1;
  const int lr = lane & 15, lk = lane >> 4;

  f32x4 acc[4][4];
#pragma unroll
  for (int m = 0; m < 4; ++m)
#pragma unroll
    for (int n = 0; n < 4; ++n) acc[m][n] = (f32x4){0.f, 0.f, 0.f, 0.f};

  const int c0 = tid, c1 = tid + 256;
  const int ar0 = c0 >> 2, as0 = c0 & 3;
  const int ar1 = c1 >> 2, as1 = c1 & 3;

  for (int k0 = 0; k0 < K; k0 += 32) {
    uint4 va0 = *(const uint4*)(A + (size_t)(m0 + ar0) * lda + k0 + as0 * 8);
    uint4 va1 = *(const uint4*)(A + (size_t)(m0 + ar1) * lda + k0 + as1 * 8);
    uint4 vb0 = *(const uint4*)(Bm + (size_t)(n0 + ar0) * ldb + k0 + as0 * 8);
    uint4 vb1 = *(const uint4*)(Bm + (size_t)(n0 + ar1) * ldb + k0 + as1 * 8);
    *(uint4*)(As + ar0 * 40 + as0 * 8) = va0;
    *(uint4*)(As + ar1 * 40 + as1 * 8) = va1;
    *(uint4*)(Bs + ar0 * 40 + as0 * 8) = vb0;
    *(uint4*)(Bs + ar1 * 40 + as1 * 8) = vb1;
    __syncthreads();
    bf16x8 af[4], bfr[4];
#pragma unroll
    for (int m = 0; m < 4; ++m)
      af[m] = *(const bf16x8*)(As + (wm * 64 + m * 16 + lr) * 40 + lk * 8);
#pragma unroll
    for (int n = 0; n < 4; ++n)
      bfr[n] = *(const bf16x8*)(Bs + (wn * 64 + n * 16 + lr) * 40 + lk * 8);
#pragma unroll
    for (int m = 0; m < 4; ++m)
#pragma unroll
      for (int n = 0; n < 4; ++n)
        acc[m][n] = __builtin_amdgcn_mfma_f32_16x16x32_bf16(af[m], bfr[n], acc[m][n], 0, 0, 0);
    __syncthreads();
  }
#pragma unroll
  for (int m = 0; m < 4; ++m) {
#pragma unroll
    for (int n = 0; n < 4; ++n) {
      const int col = n0 + wn * 64 + n * 16 + lr;
      float bv = (bias0 ? bias0[col] : 0.f) + (bias1 ? bias1[col] : 0.f);
#pragma unroll
      for (int j = 0; j < 4; ++j) {
        const int row = m0 + wm * 64 + m * 16 + lk * 4 + j;
        float v = acc[m][n][j] + bv;
        if (OUT_MODE == 0) {
          C[(size_t)row * N + col] = v;
        } else {
          int l = row >> 6, b = row & 63;
          C[((size_t)b * NDEC + l) * (size_t)N + col] = v;
        }
      }
    }
  }
}

// ---------------- device-scope grid barrier ----------------
DEV void gbar(int* cnt, int* gen, int nb) {
  __syncthreads();
  if (threadIdx.x == 0) {
    __threadfence();
    int g = __hip_atomic_load(gen, __ATOMIC_RELAXED, __HIP_MEMORY_SCOPE_AGENT);
    int a = __hip_atomic_fetch_add(cnt, 1, __ATOMIC_ACQ_REL, __HIP_MEMORY_SCOPE_AGENT);
    if (a == nb - 1) {
      __hip_atomic_store(cnt, 0, __ATOMIC_RELAXED, __HIP_MEMORY_SCOPE_AGENT);
      __hip_atomic_store(gen, g + 1, __ATOMIC_RELEASE, __HIP_MEMORY_SCOPE_AGENT);
    } else {
      while (__hip_atomic_load(gen, __ATOMIC_ACQUIRE, __HIP_MEMORY_SCOPE_AGENT) == g)
        __builtin_amdgcn_s_sleep(1);
    }
  }
  __syncthreads();
}

// ---------------- encoder: 80 LSTM steps, block bk owns hidden units {2bk,2bk+1} ----------------
__global__ __launch_bounds__(256) void k_enc(const float* __restrict__ xg,   // [B*T,2048] (+both biases)
                                             const float* __restrict__ whh,  // [2048,512]
                                             float* __restrict__ hA, float* __restrict__ hB,
                                             float* __restrict__ cfin,
                                             float* __restrict__ encf,        // [b][t][512]
                                             unsigned short* __restrict__ encbf,
                                             int* __restrict__ cnt, int* __restrict__ gen) {
  __shared__ __align__(16) float wsm[8 * 512];
  __shared__ float gsm[8 * 64];
  const int tid = threadIdx.x;
  const int u0 = blockIdx.x * 2;
  for (int idx = tid; idx < 8 * 512; idx += 256) {
    int r = idx >> 9, k = idx & 511;
    wsm[idx] = whh[(size_t)((r >> 1) * 512 + u0 + (r & 1)) * 512 + k];
  }
  __syncthreads();

  const int b = tid & 63, g = tid >> 6;
  const int uu2 = (tid >> 6) & 1;
  float cst = 0.f;

  for (int t = 0; t < T_; ++t) {
    const float* hR = (t & 1) ? hB : hA;
    float* hW = (t & 1) ? hA : hB;
    float s0 = 0.f, s1 = 0.f;
    const f32x4* hv = (const f32x4*)(hR + b * 512);
    const f32x4* w0 = (const f32x4*)(wsm + (g * 2 + 0) * 512);
    const f32x4* w1 = (const f32x4*)(wsm + (g * 2 + 1) * 512);
#pragma unroll 8
    for (int k4 = 0; k4 < 128; ++k4) {
      f32x4 h4 = hv[k4], a4 = w0[k4], b4 = w1[k4];
      s0 += h4[0] * a4[0] + h4[1] * a4[1] + h4[2] * a4[2] + h4[3] * a4[3];
      s1 += h4[0] * b4[0] + h4[1] * b4[1] + h4[2] * b4[2] + h4[3] * b4[3];
    }
    size_t xoff = ((size_t)b * T_ + t) * 2048 + g * 512 + u0;
    gsm[(g * 2 + 0) * 64 + b] = s0 + xg[xoff];
    gsm[(g * 2 + 1) * 64 + b] = s1 + xg[xoff + 1];
    __syncthreads();
    if (tid < 128) {
      float iv = gsm[(0 + uu2) * 64 + b];
      float fv = gsm[(2 + uu2) * 64 + b];
      float gv = gsm[(4 + uu2) * 64 + b];
      float ov = gsm[(6 + uu2) * 64 + b];
      cst = sigmoidf(fv) * cst + sigmoidf(iv) * tanh_fast(gv);
      float hvv = sigmoidf(ov) * tanh_fast(cst);
      int u = u0 + uu2;
      hW[b * 512 + u] = hvv;
      encf[((size_t)b * T_ + t) * 512 + u] = hvv;
      encbf[((size_t)b * T_ + t) * 512 + u] = f2bf(hvv);
      if (t == T_ - 1) cfin[b * 512 + u] = cst;
    }
    gbar(cnt, gen, gridDim.x);
  }
}

// ---------------- decoder: 30 steps x {A: hW, B: attn+softmax+ctx, C: gates+LSTM} ----------------
__global__ __launch_bounds__(256) void k_dec(const float* __restrict__ attnw,  // [512][1024]
                                             const float* __restrict__ vw,
                                             const float* __restrict__ dwih,   // [2048][1024]
                                             const float* __restrict__ dwhh,   // [2048][512]
                                             const float* __restrict__ egates, // [1920][2048]
                                             const float* __restrict__ encpart,// [B*T][512]
                                             const float* __restrict__ encf,   // [b][t][512]
                                             const float* __restrict__ cfin,
                                             float* __restrict__ hA, float* __restrict__ hB,
                                             float* __restrict__ hWbuf, float* __restrict__ ctxbuf,
                                             unsigned short* __restrict__ hsbf,
                                             int* __restrict__ cnt, int* __restrict__ gen) {
  __shared__ __align__(16) float wih2[8 * 512];
  __shared__ __align__(16) float whh[8 * 512];
  __shared__ __align__(16) float wa[2 * 512];
  __shared__ __align__(16) float vsm[512];
  __shared__ __align__(16) float hwb[512];
  __shared__ float ssm[128];
  __shared__ float gsm[8 * 64];
  const int tid = threadIdx.x;
  const int bk = blockIdx.x;
  const int u0 = bk * 2;
  for (int idx = tid; idx < 8 * 512; idx += 256) {
    int r = idx >> 9, k = idx & 511;
    int row = (r >> 1) * 512 + u0 + (r & 1);
    wih2[idx] = dwih[(size_t)row * 1024 + 512 + k];
    whh[idx] = dwhh[(size_t)row * 512 + k];
  }
  for (int idx = tid; idx < 2 * 512; idx += 256)
    wa[idx] = attnw[(size_t)(u0 + (idx >> 9)) * 1024 + (idx & 511)];
  for (int idx = tid; idx < 512; idx += 256) vsm[idx] = vw[idx];
  __syncthreads();

  const int b = tid & 63, g = tid >> 6;
  const int uu2 = (tid >> 6) & 1;
  float cst = 0.f;
  if (tid < 128) cst = cfin[b * 512 + u0 + uu2];

  for (int l = 0; l < NDEC; ++l) {
    const float* hR = (l & 1) ? hB : hA;
    float* hN = (l & 1) ? hA : hB;
    // Phase A: hW[b, u0+uu] = h . Wa_h[u0+uu]
    if (tid < 128) {
      float s = 0.f;
      const f32x4* hv = (const f32x4*)(hR + b * 512);
      const f32x4* wv = (const f32x4*)(wa + uu2 * 512);
#pragma unroll 8
      for (int k4 = 0; k4 < 128; ++k4) {
        f32x4 h4 = hv[k4], w4 = wv[k4];
        s += h4[0] * w4[0] + h4[1] * w4[1] + h4[2] * w4[2] + h4[3] * w4[3];
      }
      hWbuf[b * 512 + u0 + uu2] = s;
    }
    gbar(cnt, gen, gridDim.x);
    // Phase B (blocks 0..63): scores, softmax, ctx for batch row bk
    if (bk < 64) {
      const int bb = bk;
      for (int idx = tid; idx < 512; idx += 256) hwb[idx] = hWbuf[bb * 512 + idx];
      __syncthreads();
      const int wv_ = tid >> 6, ln = tid & 63;
      for (int ti = wv_; ti < T_; ti += 4) {
        const float* ep = encpart + ((size_t)bb * T_ + ti) * 512 + ln * 8;
        float p = 0.f;
#pragma unroll
        for (int j = 0; j < 8; ++j)
          p += vsm[ln * 8 + j] * tanh_fast(hwb[ln * 8 + j] + ep[j]);
#pragma unroll
        for (int m = 1; m < 64; m <<= 1) p += __shfl_xor(p, m, 64);
        if (ln == 0) ssm[ti] = p;
      }
      __syncthreads();
      if (tid < 64) {
        float x0 = ssm[tid];
        float x1 = (tid < T_ - 64) ? ssm[64 + tid] : -1e30f;
        float mx = fmaxf(x0, x1);
#pragma unroll
        for (int m = 1; m < 64; m <<= 1) mx = fmaxf(mx, __shfl_xor(mx, m, 64));
        float e0 = __expf(x0 - mx);
        float e1 = (tid < T_ - 64) ? __expf(x1 - mx) : 0.f;
        float sm = e0 + e1;
#pragma unroll
        for (int m = 1; m < 64; m <<= 1) sm += __shfl_xor(sm, m, 64);
        ssm[tid] = e0 / sm;
        if (tid < T_ - 64) ssm[64 + tid] = e1 / sm;
      }
      __syncthreads();
      float a0 = 0.f, a1 = 0.f;
      const float* eb = encf + (size_t)bb * T_ * 512;
      for (int ti = 0; ti < T_; ++ti) {
        float w = ssm[ti];
        a0 += w * eb[ti * 512 + tid];
        a1 += w * eb[ti * 512 + 256 + tid];
      }
      ctxbuf[bb * 512 + tid] = a0;
      ctxbuf[bb * 512 + 256 + tid] = a1;
    }
    gbar(cnt, gen, gridDim.x);
    // Phase C: gates + LSTM pointwise
    {
      float s0 = 0.f, s1 = 0.f;
      const f32x4* cv = (const f32x4*)(ctxbuf + b * 512);
      const f32x4* hv = (const f32x4*)(hR + b * 512);
      const f32x4* wi0 = (const f32x4*)(wih2 + (g * 2 + 0) * 512);
      const f32x4* wi1 = (const f32x4*)(wih2 + (g * 2 + 1) * 512);
      const f32x4* wh0 = (const f32x4*)(whh + (g * 2 + 0) * 512);
      const f32x4* wh1 = (const f32x4*)(whh + (g * 2 + 1) * 512);
#pragma unroll 4
      for (int k4 = 0; k4 < 128; ++k4) {
        f32x4 c4 = cv[k4], h4 = hv[k4];
        f32x4 x0 = wi0[k4], x1 = wi1[k4], y0 = wh0[k4], y1 = wh1[k4];
        s0 += c4[0] * x0[0] + c4[1] * x0[1] + c4[2] * x0[2] + c4[3] * x0[3]
            + h4[0] * y0[0] + h4[1] * y0[1] + h4[2] * y0[2] + h4[3] * y0[3];
        s1 += c4[0] * x1[0] + c4[1] * x1[1] + c4[2] * x1[2] + c4[3] * x1[3]
            + h4[0] * y1[0] + h4[1] * y1[1] + h4[2] * y1[2] + h4[3] * y1[3];
      }
      size_t eoff = ((size_t)l * 64 + b) * 2048 + g * 512 + u0;
      gsm[(g * 2 + 0) * 64 + b] = s0 + egates[eoff];
      gsm[(g * 2 + 1) * 64 + b] = s1 + egates[eoff + 1];
    }
    __syncthreads();
    if (tid < 128) {
      float iv = gsm[(0 + uu2) * 64 + b];
      float fv = gsm[(2 + uu2) * 64 + b];
      float gv = gsm[(4 + uu2) * 64 + b];
      float ov = gsm[(6 + uu2) * 64 + b];
      cst = sigmoidf(fv) * cst + sigmoidf(iv) * tanh_fast(gv);
      float hvv = sigmoidf(ov) * tanh_fast(cst);
      int u = u0 + uu2;
      hN[b * 512 + u] = hvv;
      hsbf[((size_t)l * 64 + b) * 512 + u] = f2bf(hvv);
    }
    gbar(cnt, gen, gridDim.x);
  }
}

// ---------------- launch ----------------
extern "C" void kernel_launch(void* const* d_in, const int* in_sizes, int n_in,
                              void* d_out, int out_size, void* d_ws, size_t ws_size,
                              hipStream_t stream) {
  const float* video = (const float*)d_in[0];
  const int* captions = (const int*)d_in[1];
  const float* emb = (const float*)d_in[2];
  const float* eWih = (const float*)d_in[3];
  const float* eWhh = (const float*)d_in[4];
  const float* ebih = (const float*)d_in[5];
  const float* ebhh = (const float*)d_in[6];
  const float* attnW = (const float*)d_in[7];
  const float* attnb = (const float*)d_in[8];
  const float* vw = (const float*)d_in[9];
  const float* dWih = (const float*)d_in[10];
  const float* dWhh = (const float*)d_in[11];
  const float* dbih = (const float*)d_in[12];
  const float* dbhh = (const float*)d_in[13];
  const float* fcW = (const float*)d_in[14];
  const float* fcb = (const float*)d_in[15];

  char* ws = (char*)d_ws;
  unsigned short* vid_bf = (unsigned short*)(ws + 0);           // 41,943,040 B (dead after K1)
  unsigned short* fcw_bf = (unsigned short*)(ws + 0);           // 32,768,000 B (after K1)
  unsigned short* hs_bf = (unsigned short*)(ws + 33554432ull);  // 1,966,080 B
  float* xg = (float*)(ws + 41943040ull);                       // 41,943,040 B (dead after enc)
  float* encpart = (float*)(ws + 41943040ull);                  // 10,485,760 B (after enc)
  float* egates = (float*)(ws + 52428800ull);                   // 15,728,640 B (after enc)
  unsigned short* aemb = (unsigned short*)(ws + 68157440ull);   // 1,966,080 B (after enc)
  unsigned short* ewih_bf = (unsigned short*)(ws + 83886080ull);// 16,777,216 B
  float* encf = (float*)(ws + 100663296ull);                    // 10,485,760 B
  unsigned short* encbf = (unsigned short*)(ws + 111149056ull); // 5,242,880 B
  unsigned short* attnw_bf = (unsigned short*)(ws + 116391936ull); // 1,048,576 B
  unsigned short* dwih_bf = (unsigned short*)(ws + 117440512ull);  // 4,194,304 B
  float* hA = (float*)(ws + 121634816ull);
  float* hB = (float*)(ws + 121765888ull);
  float* cfin = (float*)(ws + 121896960ull);
  float* hWbuf = (float*)(ws + 122028032ull);
  float* ctxbuf = (float*)(ws + 122159104ull);
  int* bar = (int*)(ws + 122290176ull);
  int* flag = (int*)(ws + 122290432ull);

  hipMemsetAsync(ws + 121634816ull, 0, 122290688ull - 121634816ull, stream);

  auto cvt = [&](const float* in, unsigned short* out, long n) {
    long n4 = n / 4;
    int blocks = (int)((n4 + 255) / 256);
    if (blocks > 2048) blocks = 2048;
    k_cvt<<<blocks, 256, 0, stream>>>(in, out, n4);
  };
  cvt(video, vid_bf, 5120L * 4096);
  cvt(eWih, ewih_bf, 2048L * 4096);
  cvt(attnW, attnw_bf, 512L * 1024);
  cvt(dWih, dwih_bf, 2048L * 1024);
  k_detect_i64<<<1, 256, 0, stream>>>(captions, flag);

  // K1: X_gates = video @ enc_Wih^T + ebih + ebhh   [5120 x 2048]
  k_gemm<0><<<dim3(16, 40), 256, 0, stream>>>(vid_bf, 4096, ewih_bf, 4096, xg, 2048, 4096, ebih, ebhh);
  cvt(fcW, fcw_bf, 32000L * 512);

  k_enc<<<256, 256, 0, stream>>>(xg, eWhh, hA, hB, cfin, encf, encbf, bar, bar + 1);

  k_gather_emb<<<1920, 256, 0, stream>>>(emb, captions, flag, aemb);
  // EncPart = enc_out @ attn_W[:,512:]^T + attn_b   [5120 x 512]
  k_gemm<0><<<dim3(4, 40), 256, 0, stream>>>(encbf, 512, attnw_bf + 512, 1024, encpart, 512, 512, attnb, nullptr);
  // E_gates = emb[tok] @ dec_Wih[:,:512]^T + dbih + dbhh   [1920 x 2048]
  k_gemm<0><<<dim3(16, 15), 256, 0, stream>>>(aemb, 512, dwih_bf, 1024, egates, 2048, 512, dbih, dbhh);

  k_dec<<<256, 256, 0, stream>>>(attnW, vw, dWih, dWhh, egates, encpart, encf, cfin,
                                 hA, hB, hWbuf, ctxbuf, hs_bf, bar, bar + 1);

  // FC: out[b][l][v] = Hs @ fc_W^T + fc_b   [1920 x 32000]
  k_gemm<1><<<dim3(250, 15), 256, 0, stream>>>(hs_bf, 512, fcw_bf, 512, (float*)d_out, 32000, 512, fcb, nullptr);
}

// Round 2
// 7612.074 us; speedup vs baseline: 1.5068x; 1.5068x over previous
//
#include <hip/hip_runtime.h>

// S2VT + attention, decomposed:
//  1. cvt fp32->bf16 (video, enc_Wih, attn_W, dec_Wih, fc_W)
//  2. K1 GEMM: X_gates[b*80+t, 2048] = video @ enc_Wih^T + bih + bhh   (bf16 MFMA)
//  3. k_enc persistent: 80 LSTM steps, grid barrier per step; writes enc_out (f32+bf16), final h,c
//  4. EncPart GEMM: enc_out @ attn_W[:,512:]^T + attn_b
//     E_gates GEMM: emb[tok] @ dec_Wih[:,:512]^T + dbih + dbhh
//  5. k_dec persistent: 30 steps x {hW, attention+softmax+ctx, gates+LSTM}; writes Hs bf16
//  6. FC GEMM: Hs @ fc_W^T + fc_b -> out[b][l][v]   (bf16 MFMA)
//
// R1 fix: gbar spin used ACQUIRE@AGENT per poll -> per-poll L1/L2 invalidate
// (79us/barrier, L2 thrash). Now: relaxed polls, ONE acquire fence on exit,
// release carried by the ACQ_REL fetch_add (threadfence removed).

#define DEV __device__ __forceinline__

typedef __attribute__((ext_vector_type(4))) float f32x4;
typedef __attribute__((ext_vector_type(8))) short bf16x8;

static constexpr int B_ = 64, T_ = 80, H_ = 512, L_ = 31, NDEC = 30;

DEV unsigned short f2bf(float f) {
  unsigned u = __builtin_bit_cast(unsigned, f);
  u += 0x7FFF + ((u >> 16) & 1);
  return (unsigned short)(u >> 16);
}
DEV float sigmoidf(float x) { return 1.f / (1.f + __expf(-x)); }
DEV float tanh_fast(float x) { float e = __expf(2.f * x); return (e - 1.f) / (e + 1.f); }

// ---------------- fp32 -> bf16 convert ----------------
__global__ __launch_bounds__(256) void k_cvt(const float* __restrict__ in,
                                             unsigned short* __restrict__ out, long n4) {
  long i = (long)blockIdx.x * 256 + threadIdx.x;
  long stride = (long)gridDim.x * 256;
  for (; i < n4; i += stride) {
    float4 v = reinterpret_cast<const float4*>(in)[i];
    ushort4 o;
    o.x = f2bf(v.x); o.y = f2bf(v.y); o.z = f2bf(v.z); o.w = f2bf(v.w);
    reinterpret_cast<ushort4*>(out)[i] = o;
  }
}

// ---------------- int64-vs-int32 caption detect ----------------
__global__ void k_detect_i64(const int* __restrict__ cap, int* __restrict__ flag) {
  __shared__ int s;
  if (threadIdx.x == 0) s = 0;
  __syncthreads();
  int acc = 0;
  for (int i = threadIdx.x; i < (B_ * L_) / 2; i += 256) acc |= cap[2 * i + 1];
  if (acc) atomicOr(&s, 1);
  __syncthreads();
  if (threadIdx.x == 0) flag[0] = (s == 0) ? 1 : 0;  // all-high-words-zero => int64
}

// ---------------- embedding gather (rows r = l*64+b) ----------------
__global__ __launch_bounds__(256) void k_gather_emb(const float* __restrict__ emb,
                                                    const int* __restrict__ cap,
                                                    const int* __restrict__ flag,
                                                    unsigned short* __restrict__ aemb) {
  int r = blockIdx.x;            // 0..1919
  int l = r >> 6, b = r & 63;
  int ci = b * L_ + l;
  int tok = flag[0] ? cap[2 * ci] : cap[ci];
  const float* src = emb + (size_t)tok * H_;
  unsigned short* dst = aemb + (size_t)r * H_;
  for (int c = threadIdx.x; c < H_; c += 256) dst[c] = f2bf(src[c]);
}

// ---------------- bf16 MFMA GEMM: C[M,N] = A[M,K] * B[N,K]^T + bias ----------------
// 128x128 tile, BK=32, 4 waves (each 64x64 = 4x4 fragments of 16x16x32).
// LDS row pitch 40 shorts (80B) to break the 64B-stride bank conflict.
template <int OUT_MODE>  // 0: row-major ldc=N ; 1: row r=(l*64+b) -> out[(b*30+l)*N + col]
__global__ __launch_bounds__(256) void k_gemm(const unsigned short* __restrict__ A, int lda,
                                              const unsigned short* __restrict__ Bm, int ldb,
                                              float* __restrict__ C, int N, int K,
                                              const float* __restrict__ bias0,
                                              const float* __restrict__ bias1) {
  __shared__ __align__(16) unsigned short As[128 * 40];
  __shared__ __align__(16) unsigned short Bs[128 * 40];
  const int tid = threadIdx.x;
  const int m0 = blockIdx.y * 128, n0 = blockIdx.x * 128;
  const int wave = tid >> 6, lane = tid & 63;
  const int wm = wave >> 1, wn = wave & 1;
  const int lr = lane & 15, lk = lane >> 4;

  f32x4 acc[4][4];
#pragma unroll
  for (int m = 0; m < 4; ++m)
#pragma unroll
    for (int n = 0; n < 4; ++n) acc[m][n] = (f32x4){0.f, 0.f, 0.f, 0.f};

  const int c0 = tid, c1 = tid + 256;
  const int ar0 = c0 >> 2, as0 = c0 & 3;
  const int ar1 = c1 >> 2, as1 = c1 & 3;

  for (int k0 = 0; k0 < K; k0 += 32) {
    uint4 va0 = *(const uint4*)(A + (size_t)(m0 + ar0) * lda + k0 + as0 * 8);
    uint4 va1 = *(const uint4*)(A + (size_t)(m0 + ar1) * lda + k0 + as1 * 8);
    uint4 vb0 = *(const uint4*)(Bm + (size_t)(n0 + ar0) * ldb + k0 + as0 * 8);
    uint4 vb1 = *(const uint4*)(Bm + (size_t)(n0 + ar1) * ldb + k0 + as1 * 8);
    *(uint4*)(As + ar0 * 40 + as0 * 8) = va0;
    *(uint4*)(As + ar1 * 40 + as1 * 8) = va1;
    *(uint4*)(Bs + ar0 * 40 + as0 * 8) = vb0;
    *(uint4*)(Bs + ar1 * 40 + as1 * 8) = vb1;
    __syncthreads();
    bf16x8 af[4], bfr[4];
#pragma unroll
    for (int m = 0; m < 4; ++m)
      af[m] = *(const bf16x8*)(As + (wm * 64 + m * 16 + lr) * 40 + lk * 8);
#pragma unroll
    for (int n = 0; n < 4; ++n)
      bfr[n] = *(const bf16x8*)(Bs + (wn * 64 + n * 16 + lr) * 40 + lk * 8);
#pragma unroll
    for (int m = 0; m < 4; ++m)
#pragma unroll
      for (int n = 0; n < 4; ++n)
        acc[m][n] = __builtin_amdgcn_mfma_f32_16x16x32_bf16(af[m], bfr[n], acc[m][n], 0, 0, 0);
    __syncthreads();
  }
#pragma unroll
  for (int m = 0; m < 4; ++m) {
#pragma unroll
    for (int n = 0; n < 4; ++n) {
      const int col = n0 + wn * 64 + n * 16 + lr;
      float bv = (bias0 ? bias0[col] : 0.f) + (bias1 ? bias1[col] : 0.f);
#pragma unroll
      for (int j = 0; j < 4; ++j) {
        const int row = m0 + wm * 64 + m * 16 + lk * 4 + j;
        float v = acc[m][n][j] + bv;
        if (OUT_MODE == 0) {
          C[(size_t)row * N + col] = v;
        } else {
          int l = row >> 6, b = row & 63;
          C[((size_t)b * NDEC + l) * (size_t)N + col] = v;
        }
      }
    }
  }
}

// ---------------- device-scope grid barrier (relaxed spin, one acquire on exit) ----------------
DEV void gbar(int* cnt, int* gen, int nb) {
  __syncthreads();
  if (threadIdx.x == 0) {
    int g = __hip_atomic_load(gen, __ATOMIC_RELAXED, __HIP_MEMORY_SCOPE_AGENT);
    // ACQ_REL RMW: releases this block's prior writes (drain + L2 writeback),
    // acquires all earlier blocks' releases for the last-arriver.
    int a = __hip_atomic_fetch_add(cnt, 1, __ATOMIC_ACQ_REL, __HIP_MEMORY_SCOPE_AGENT);
    if (a == nb - 1) {
      __hip_atomic_store(cnt, 0, __ATOMIC_RELAXED, __HIP_MEMORY_SCOPE_AGENT);
      __hip_atomic_store(gen, g + 1, __ATOMIC_RELEASE, __HIP_MEMORY_SCOPE_AGENT);
    } else {
      // RELAXED polls: no per-iteration cache invalidate.
      while (__hip_atomic_load(gen, __ATOMIC_RELAXED, __HIP_MEMORY_SCOPE_AGENT) == g)
        __builtin_amdgcn_s_sleep(2);
      // ONE acquire fence after observing the release store.
      __builtin_amdgcn_fence(__ATOMIC_ACQUIRE, "agent");
    }
  }
  __syncthreads();
}

// ---------------- encoder: 80 LSTM steps, block bk owns hidden units {2bk,2bk+1} ----------------
__global__ __launch_bounds__(256) void k_enc(const float* __restrict__ xg,   // [B*T,2048] (+both biases)
                                             const float* __restrict__ whh,  // [2048,512]
                                             float* __restrict__ hA, float* __restrict__ hB,
                                             float* __restrict__ cfin,
                                             float* __restrict__ encf,        // [b][t][512]
                                             unsigned short* __restrict__ encbf,
                                             int* __restrict__ cnt, int* __restrict__ gen) {
  __shared__ __align__(16) float wsm[8 * 512];
  __shared__ float gsm[8 * 64];
  const int tid = threadIdx.x;
  const int u0 = blockIdx.x * 2;
  for (int idx = tid; idx < 8 * 512; idx += 256) {
    int r = idx >> 9, k = idx & 511;
    wsm[idx] = whh[(size_t)((r >> 1) * 512 + u0 + (r & 1)) * 512 + k];
  }
  __syncthreads();

  const int b = tid & 63, g = tid >> 6;
  const int uu2 = (tid >> 6) & 1;
  float cst = 0.f;

  for (int t = 0; t < T_; ++t) {
    const float* hR = (t & 1) ? hB : hA;
    float* hW = (t & 1) ? hA : hB;
    float s0 = 0.f, s1 = 0.f;
    const f32x4* hv = (const f32x4*)(hR + b * 512);
    const f32x4* w0 = (const f32x4*)(wsm + (g * 2 + 0) * 512);
    const f32x4* w1 = (const f32x4*)(wsm + (g * 2 + 1) * 512);
#pragma unroll 8
    for (int k4 = 0; k4 < 128; ++k4) {
      f32x4 h4 = hv[k4], a4 = w0[k4], b4 = w1[k4];
      s0 += h4[0] * a4[0] + h4[1] * a4[1] + h4[2] * a4[2] + h4[3] * a4[3];
      s1 += h4[0] * b4[0] + h4[1] * b4[1] + h4[2] * b4[2] + h4[3] * b4[3];
    }
    size_t xoff = ((size_t)b * T_ + t) * 2048 + g * 512 + u0;
    gsm[(g * 2 + 0) * 64 + b] = s0 + xg[xoff];
    gsm[(g * 2 + 1) * 64 + b] = s1 + xg[xoff + 1];
    __syncthreads();
    if (tid < 128) {
      float iv = gsm[(0 + uu2) * 64 + b];
      float fv = gsm[(2 + uu2) * 64 + b];
      float gv = gsm[(4 + uu2) * 64 + b];
      float ov = gsm[(6 + uu2) * 64 + b];
      cst = sigmoidf(fv) * cst + sigmoidf(iv) * tanh_fast(gv);
      float hvv = sigmoidf(ov) * tanh_fast(cst);
      int u = u0 + uu2;
      hW[b * 512 + u] = hvv;
      encf[((size_t)b * T_ + t) * 512 + u] = hvv;
      encbf[((size_t)b * T_ + t) * 512 + u] = f2bf(hvv);
      if (t == T_ - 1) cfin[b * 512 + u] = cst;
    }
    gbar(cnt, gen, gridDim.x);
  }
}

// ---------------- decoder: 30 steps x {A: hW, B: attn+softmax+ctx, C: gates+LSTM} ----------------
__global__ __launch_bounds__(256) void k_dec(const float* __restrict__ attnw,  // [512][1024]
                                             const float* __restrict__ vw,
                                             const float* __restrict__ dwih,   // [2048][1024]
                                             const float* __restrict__ dwhh,   // [2048][512]
                                             const float* __restrict__ egates, // [1920][2048]
                                             const float* __restrict__ encpart,// [B*T][512]
                                             const float* __restrict__ encf,   // [b][t][512]
                                             const float* __restrict__ cfin,
                                             float* __restrict__ hA, float* __restrict__ hB,
                                             float* __restrict__ hWbuf, float* __restrict__ ctxbuf,
                                             unsigned short* __restrict__ hsbf,
                                             int* __restrict__ cnt, int* __restrict__ gen) {
  __shared__ __align__(16) float wih2[8 * 512];
  __shared__ __align__(16) float whh[8 * 512];
  __shared__ __align__(16) float wa[2 * 512];
  __shared__ __align__(16) float vsm[512];
  __shared__ __align__(16) float hwb[512];
  __shared__ float ssm[128];
  __shared__ float gsm[8 * 64];
  const int tid = threadIdx.x;
  const int bk = blockIdx.x;
  const int u0 = bk * 2;
  for (int idx = tid; idx < 8 * 512; idx += 256) {
    int r = idx >> 9, k = idx & 511;
    int row = (r >> 1) * 512 + u0 + (r & 1);
    wih2[idx] = dwih[(size_t)row * 1024 + 512 + k];
    whh[idx] = dwhh[(size_t)row * 512 + k];
  }
  for (int idx = tid; idx < 2 * 512; idx += 256)
    wa[idx] = attnw[(size_t)(u0 + (idx >> 9)) * 1024 + (idx & 511)];
  for (int idx = tid; idx < 512; idx += 256) vsm[idx] = vw[idx];
  __syncthreads();

  const int b = tid & 63, g = tid >> 6;
  const int uu2 = (tid >> 6) & 1;
  float cst = 0.f;
  if (tid < 128) cst = cfin[b * 512 + u0 + uu2];

  for (int l = 0; l < NDEC; ++l) {
    const float* hR = (l & 1) ? hB : hA;
    float* hN = (l & 1) ? hA : hB;
    // Phase A: hW[b, u0+uu] = h . Wa_h[u0+uu]
    if (tid < 128) {
      float s = 0.f;
      const f32x4* hv = (const f32x4*)(hR + b * 512);
      const f32x4* wv = (const f32x4*)(wa + uu2 * 512);
#pragma unroll 8
      for (int k4 = 0; k4 < 128; ++k4) {
        f32x4 h4 = hv[k4], w4 = wv[k4];
        s += h4[0] * w4[0] + h4[1] * w4[1] + h4[2] * w4[2] + h4[3] * w4[3];
      }
      hWbuf[b * 512 + u0 + uu2] = s;
    }
    gbar(cnt, gen, gridDim.x);
    // Phase B (blocks 0..63): scores, softmax, ctx for batch row bk
    if (bk < 64) {
      const int bb = bk;
      for (int idx = tid; idx < 512; idx += 256) hwb[idx] = hWbuf[bb * 512 + idx];
      __syncthreads();
      const int wv_ = tid >> 6, ln = tid & 63;
      for (int ti = wv_; ti < T_; ti += 4) {
        const float* ep = encpart + ((size_t)bb * T_ + ti) * 512 + ln * 8;
        float p = 0.f;
#pragma unroll
        for (int j = 0; j < 8; ++j)
          p += vsm[ln * 8 + j] * tanh_fast(hwb[ln * 8 + j] + ep[j]);
#pragma unroll
        for (int m = 1; m < 64; m <<= 1) p += __shfl_xor(p, m, 64);
        if (ln == 0) ssm[ti] = p;
      }
      __syncthreads();
      if (tid < 64) {
        float x0 = ssm[tid];
        float x1 = (tid < T_ - 64) ? ssm[64 + tid] : -1e30f;
        float mx = fmaxf(x0, x1);
#pragma unroll
        for (int m = 1; m < 64; m <<= 1) mx = fmaxf(mx, __shfl_xor(mx, m, 64));
        float e0 = __expf(x0 - mx);
        float e1 = (tid < T_ - 64) ? __expf(x1 - mx) : 0.f;
        float sm = e0 + e1;
#pragma unroll
        for (int m = 1; m < 64; m <<= 1) sm += __shfl_xor(sm, m, 64);
        ssm[tid] = e0 / sm;
        if (tid < T_ - 64) ssm[64 + tid] = e1 / sm;
      }
      __syncthreads();
      float a0 = 0.f, a1 = 0.f;
      const float* eb = encf + (size_t)bb * T_ * 512;
      for (int ti = 0; ti < T_; ++ti) {
        float w = ssm[ti];
        a0 += w * eb[ti * 512 + tid];
        a1 += w * eb[ti * 512 + 256 + tid];
      }
      ctxbuf[bb * 512 + tid] = a0;
      ctxbuf[bb * 512 + 256 + tid] = a1;
    }
    gbar(cnt, gen, gridDim.x);
    // Phase C: gates + LSTM pointwise
    {
      float s0 = 0.f, s1 = 0.f;
      const f32x4* cv = (const f32x4*)(ctxbuf + b * 512);
      const f32x4* hv = (const f32x4*)(hR + b * 512);
      const f32x4* wi0 = (const f32x4*)(wih2 + (g * 2 + 0) * 512);
      const f32x4* wi1 = (const f32x4*)(wih2 + (g * 2 + 1) * 512);
      const f32x4* wh0 = (const f32x4*)(whh + (g * 2 + 0) * 512);
      const f32x4* wh1 = (const f32x4*)(whh + (g * 2 + 1) * 512);
#pragma unroll 4
      for (int k4 = 0; k4 < 128; ++k4) {
        f32x4 c4 = cv[k4], h4 = hv[k4];
        f32x4 x0 = wi0[k4], x1 = wi1[k4], y0 = wh0[k4], y1 = wh1[k4];
        s0 += c4[0] * x0[0] + c4[1] * x0[1] + c4[2] * x0[2] + c4[3] * x0[3]
            + h4[0] * y0[0] + h4[1] * y0[1] + h4[2] * y0[2] + h4[3] * y0[3];
        s1 += c4[0] * x1[0] + c4[1] * x1[1] + c4[2] * x1[2] + c4[3] * x1[3]
            + h4[0] * y1[0] + h4[1] * y1[1] + h4[2] * y1[2] + h4[3] * y1[3];
      }
      size_t eoff = ((size_t)l * 64 + b) * 2048 + g * 512 + u0;
      gsm[(g * 2 + 0) * 64 + b] = s0 + egates[eoff];
      gsm[(g * 2 + 1) * 64 + b] = s1 + egates[eoff + 1];
    }
    __syncthreads();
    if (tid < 128) {
      float iv = gsm[(0 + uu2) * 64 + b];
      float fv = gsm[(2 + uu2) * 64 + b];
      float gv = gsm[(4 + uu2) * 64 + b];
      float ov = gsm[(6 + uu2) * 64 + b];
      cst = sigmoidf(fv) * cst + sigmoidf(iv) * tanh_fast(gv);
      float hvv = sigmoidf(ov) * tanh_fast(cst);
      int u = u0 + uu2;
      hN[b * 512 + u] = hvv;
      hsbf[((size_t)l * 64 + b) * 512 + u] = f2bf(hvv);
    }
    gbar(cnt, gen, gridDim.x);
  }
}

// ---------------- launch ----------------
extern "C" void kernel_launch(void* const* d_in, const int* in_sizes, int n_in,
                              void* d_out, int out_size, void* d_ws, size_t ws_size,
                              hipStream_t stream) {
  const float* video = (const float*)d_in[0];
  const int* captions = (const int*)d_in[1];
  const float* emb = (const float*)d_in[2];
  const float* eWih = (const float*)d_in[3];
  const float* eWhh = (const float*)d_in[4];
  const float* ebih = (const float*)d_in[5];
  const float* ebhh = (const float*)d_in[6];
  const float* attnW = (const float*)d_in[7];
  const float* attnb = (const float*)d_in[8];
  const float* vw = (const float*)d_in[9];
  const float* dWih = (const float*)d_in[10];
  const float* dWhh = (const float*)d_in[11];
  const float* dbih = (const float*)d_in[12];
  const float* dbhh = (const float*)d_in[13];
  const float* fcW = (const float*)d_in[14];
  const float* fcb = (const float*)d_in[15];

  char* ws = (char*)d_ws;
  unsigned short* vid_bf = (unsigned short*)(ws + 0);           // 41,943,040 B (dead after K1)
  unsigned short* fcw_bf = (unsigned short*)(ws + 0);           // 32,768,000 B (after K1)
  unsigned short* hs_bf = (unsigned short*)(ws + 33554432ull);  // 1,966,080 B
  float* xg = (float*)(ws + 41943040ull);                       // 41,943,040 B (dead after enc)
  float* encpart = (float*)(ws + 41943040ull);                  // 10,485,760 B (after enc)
  float* egates = (float*)(ws + 52428800ull);                   // 15,728,640 B (after enc)
  unsigned short* aemb = (unsigned short*)(ws + 68157440ull);   // 1,966,080 B (after enc)
  unsigned short* ewih_bf = (unsigned short*)(ws + 83886080ull);// 16,777,216 B
  float* encf = (float*)(ws + 100663296ull);                    // 10,485,760 B
  unsigned short* encbf = (unsigned short*)(ws + 111149056ull); // 5,242,880 B
  unsigned short* attnw_bf = (unsigned short*)(ws + 116391936ull); // 1,048,576 B
  unsigned short* dwih_bf = (unsigned short*)(ws + 117440512ull);  // 4,194,304 B
  float* hA = (float*)(ws + 121634816ull);
  float* hB = (float*)(ws + 121765888ull);
  float* cfin = (float*)(ws + 121896960ull);
  float* hWbuf = (float*)(ws + 122028032ull);
  float* ctxbuf = (float*)(ws + 122159104ull);
  int* bar = (int*)(ws + 122290176ull);
  int* flag = (int*)(ws + 122290432ull);

  hipMemsetAsync(ws + 121634816ull, 0, 122290688ull - 121634816ull, stream);

  auto cvt = [&](const float* in, unsigned short* out, long n) {
    long n4 = n / 4;
    int blocks = (int)((n4 + 255) / 256);
    if (blocks > 2048) blocks = 2048;
    k_cvt<<<blocks, 256, 0, stream>>>(in, out, n4);
  };
  cvt(video, vid_bf, 5120L * 4096);
  cvt(eWih, ewih_bf, 2048L * 4096);
  cvt(attnW, attnw_bf, 512L * 1024);
  cvt(dWih, dwih_bf, 2048L * 1024);
  k_detect_i64<<<1, 256, 0, stream>>>(captions, flag);

  // K1: X_gates = video @ enc_Wih^T + ebih + ebhh   [5120 x 2048]
  k_gemm<0><<<dim3(16, 40), 256, 0, stream>>>(vid_bf, 4096, ewih_bf, 4096, xg, 2048, 4096, ebih, ebhh);
  cvt(fcW, fcw_bf, 32000L * 512);

  k_enc<<<256, 256, 0, stream>>>(xg, eWhh, hA, hB, cfin, encf, encbf, bar, bar + 1);

  k_gather_emb<<<1920, 256, 0, stream>>>(emb, captions, flag, aemb);
  // EncPart = enc_out @ attn_W[:,512:]^T + attn_b   [5120 x 512]
  k_gemm<0><<<dim3(4, 40), 256, 0, stream>>>(encbf, 512, attnw_bf + 512, 1024, encpart, 512, 512, attnb, nullptr);
  // E_gates = emb[tok] @ dec_Wih[:,:512]^T + dbih + dbhh   [1920 x 2048]
  k_gemm<0><<<dim3(16, 15), 256, 0, stream>>>(aemb, 512, dwih_bf, 1024, egates, 2048, 512, dbih, dbhh);

  k_dec<<<256, 256, 0, stream>>>(attnW, vw, dWih, dWhh, egates, encpart, encf, cfin,
                                 hA, hB, hWbuf, ctxbuf, hs_bf, bar, bar + 1);

  // FC: out[b][l][v] = Hs @ fc_W^T + fc_b   [1920 x 32000]
  k_gemm<1><<<dim3(250, 15), 256, 0, stream>>>(hs_bf, 512, fcw_bf, 512, (float*)d_out, 32000, 512, fcb, nullptr);
}

// Round 3
// 5558.314 us; speedup vs baseline: 2.0635x; 1.3695x over previous
//
#include <hip/hip_runtime.h>

// S2VT + attention, decomposed:
//  1. cvt fp32->bf16 (video, enc_Wih, attn_W, dec_Wih, fc_W)
//  2. K1 GEMM: X_gates[b*80+t, 2048] = video @ enc_Wih^T + bih + bhh   (bf16 MFMA)
//  3. k_enc persistent: 80 LSTM steps, grid barrier per step; writes enc_out (f32+bf16), final h,c
//  4. EncPart GEMM: enc_out @ attn_W[:,512:]^T + attn_b
//     E_gates GEMM: emb[tok] @ dec_Wih[:,:512]^T + dbih + dbhh
//  5. k_dec persistent: 30 steps x {hW, attention+softmax+ctx, gates+LSTM}; writes Hs bf16
//  6. FC GEMM: Hs @ fc_W^T + fc_b -> out[b][l][v]   (bf16 MFMA)
//
// R1: per-poll ACQUIRE@AGENT invalidates -> 79us/barrier. R2: relaxed polls ->
// 41.7us/barrier, dominated by 256 same-line ACQ_REL fetch_adds (serialized RMW
// at the coherence point, ~150ns each). R3: flags-array barrier -- each block
// release-stores its OWN flag (parallel, no contention), block 0 aggregates with
// 256 parallel polls, one release store of gen, one acquire fence on exit.

#define DEV __device__ __forceinline__

typedef __attribute__((ext_vector_type(4))) float f32x4;
typedef __attribute__((ext_vector_type(8))) short bf16x8;

static constexpr int B_ = 64, T_ = 80, H_ = 512, L_ = 31, NDEC = 30;

DEV unsigned short f2bf(float f) {
  unsigned u = __builtin_bit_cast(unsigned, f);
  u += 0x7FFF + ((u >> 16) & 1);
  return (unsigned short)(u >> 16);
}
DEV float sigmoidf(float x) { return 1.f / (1.f + __expf(-x)); }
DEV float tanh_fast(float x) { float e = __expf(2.f * x); return (e - 1.f) / (e + 1.f); }

// ---------------- fp32 -> bf16 convert ----------------
__global__ __launch_bounds__(256) void k_cvt(const float* __restrict__ in,
                                             unsigned short* __restrict__ out, long n4) {
  long i = (long)blockIdx.x * 256 + threadIdx.x;
  long stride = (long)gridDim.x * 256;
  for (; i < n4; i += stride) {
    float4 v = reinterpret_cast<const float4*>(in)[i];
    ushort4 o;
    o.x = f2bf(v.x); o.y = f2bf(v.y); o.z = f2bf(v.z); o.w = f2bf(v.w);
    reinterpret_cast<ushort4*>(out)[i] = o;
  }
}

// ---------------- int64-vs-int32 caption detect ----------------
__global__ void k_detect_i64(const int* __restrict__ cap, int* __restrict__ flag) {
  __shared__ int s;
  if (threadIdx.x == 0) s = 0;
  __syncthreads();
  int acc = 0;
  for (int i = threadIdx.x; i < (B_ * L_) / 2; i += 256) acc |= cap[2 * i + 1];
  if (acc) atomicOr(&s, 1);
  __syncthreads();
  if (threadIdx.x == 0) flag[0] = (s == 0) ? 1 : 0;  // all-high-words-zero => int64
}

// ---------------- embedding gather (rows r = l*64+b) ----------------
__global__ __launch_bounds__(256) void k_gather_emb(const float* __restrict__ emb,
                                                    const int* __restrict__ cap,
                                                    const int* __restrict__ flag,
                                                    unsigned short* __restrict__ aemb) {
  int r = blockIdx.x;            // 0..1919
  int l = r >> 6, b = r & 63;
  int ci = b * L_ + l;
  int tok = flag[0] ? cap[2 * ci] : cap[ci];
  const float* src = emb + (size_t)tok * H_;
  unsigned short* dst = aemb + (size_t)r * H_;
  for (int c = threadIdx.x; c < H_; c += 256) dst[c] = f2bf(src[c]);
}

// ---------------- bf16 MFMA GEMM: C[M,N] = A[M,K] * B[N,K]^T + bias ----------------
// 128x128 tile, BK=32, 4 waves (each 64x64 = 4x4 fragments of 16x16x32).
// LDS row pitch 40 shorts (80B) to break the 64B-stride bank conflict.
template <int OUT_MODE>  // 0: row-major ldc=N ; 1: row r=(l*64+b) -> out[(b*30+l)*N + col]
__global__ __launch_bounds__(256) void k_gemm(const unsigned short* __restrict__ A, int lda,
                                              const unsigned short* __restrict__ Bm, int ldb,
                                              float* __restrict__ C, int N, int K,
                                              const float* __restrict__ bias0,
                                              const float* __restrict__ bias1) {
  __shared__ __align__(16) unsigned short As[128 * 40];
  __shared__ __align__(16) unsigned short Bs[128 * 40];
  const int tid = threadIdx.x;
  const int m0 = blockIdx.y * 128, n0 = blockIdx.x * 128;
  const int wave = tid >> 6, lane = tid & 63;
  const int wm = wave >> 1, wn = wave & 1;
  const int lr = lane & 15, lk = lane >> 4;

  f32x4 acc[4][4];
#pragma unroll
  for (int m = 0; m < 4; ++m)
#pragma unroll
    for (int n = 0; n < 4; ++n) acc[m][n] = (f32x4){0.f, 0.f, 0.f, 0.f};

  const int c0 = tid, c1 = tid + 256;
  const int ar0 = c0 >> 2, as0 = c0 & 3;
  const int ar1 = c1 >> 2, as1 = c1 & 3;

  for (int k0 = 0; k0 < K; k0 += 32) {
    uint4 va0 = *(const uint4*)(A + (size_t)(m0 + ar0) * lda + k0 + as0 * 8);
    uint4 va1 = *(const uint4*)(A + (size_t)(m0 + ar1) * lda + k0 + as1 * 8);
    uint4 vb0 = *(const uint4*)(Bm + (size_t)(n0 + ar0) * ldb + k0 + as0 * 8);
    uint4 vb1 = *(const uint4*)(Bm + (size_t)(n0 + ar1) * ldb + k0 + as1 * 8);
    *(uint4*)(As + ar0 * 40 + as0 * 8) = va0;
    *(uint4*)(As + ar1 * 40 + as1 * 8) = va1;
    *(uint4*)(Bs + ar0 * 40 + as0 * 8) = vb0;
    *(uint4*)(Bs + ar1 * 40 + as1 * 8) = vb1;
    __syncthreads();
    bf16x8 af[4], bfr[4];
#pragma unroll
    for (int m = 0; m < 4; ++m)
      af[m] = *(const bf16x8*)(As + (wm * 64 + m * 16 + lr) * 40 + lk * 8);
#pragma unroll
    for (int n = 0; n < 4; ++n)
      bfr[n] = *(const bf16x8*)(Bs + (wn * 64 + n * 16 + lr) * 40 + lk * 8);
#pragma unroll
    for (int m = 0; m < 4; ++m)
#pragma unroll
      for (int n = 0; n < 4; ++n)
        acc[m][n] = __builtin_amdgcn_mfma_f32_16x16x32_bf16(af[m], bfr[n], acc[m][n], 0, 0, 0);
    __syncthreads();
  }
#pragma unroll
  for (int m = 0; m < 4; ++m) {
#pragma unroll
    for (int n = 0; n < 4; ++n) {
      const int col = n0 + wn * 64 + n * 16 + lr;
      float bv = (bias0 ? bias0[col] : 0.f) + (bias1 ? bias1[col] : 0.f);
#pragma unroll
      for (int j = 0; j < 4; ++j) {
        const int row = m0 + wm * 64 + m * 16 + lk * 4 + j;
        float v = acc[m][n][j] + bv;
        if (OUT_MODE == 0) {
          C[(size_t)row * N + col] = v;
        } else {
          int l = row >> 6, b = row & 63;
          C[((size_t)b * NDEC + l) * (size_t)N + col] = v;
        }
      }
    }
  }
}

// ---------------- flags-array grid barrier (no same-line RMW contention) ----------------
// Block i release-stores flags[i]=ph (parallel across blocks). Block 0's threads
// poll all flags, then release-store gen=ph. Waiters poll gen relaxed, then ONE
// acquire fence. ph must increase monotonically across calls; buffers zeroed at launch.
DEV void gbar(int* __restrict__ flags, int* __restrict__ gen, int nb, int ph) {
  __syncthreads();
  if (blockIdx.x == 0) {
    for (int t = threadIdx.x; t < nb; t += 256)
      if (t > 0)
        while (__hip_atomic_load(flags + t, __ATOMIC_RELAXED, __HIP_MEMORY_SCOPE_AGENT) < ph)
          __builtin_amdgcn_s_sleep(1);
    __syncthreads();
    if (threadIdx.x == 0) {
      __hip_atomic_store(gen, ph, __ATOMIC_RELEASE, __HIP_MEMORY_SCOPE_AGENT);
      __builtin_amdgcn_fence(__ATOMIC_ACQUIRE, "agent");
    }
  } else {
    if (threadIdx.x == 0) {
      __hip_atomic_store(flags + blockIdx.x, ph, __ATOMIC_RELEASE, __HIP_MEMORY_SCOPE_AGENT);
      while (__hip_atomic_load(gen, __ATOMIC_RELAXED, __HIP_MEMORY_SCOPE_AGENT) < ph)
        __builtin_amdgcn_s_sleep(1);
      __builtin_amdgcn_fence(__ATOMIC_ACQUIRE, "agent");
    }
  }
  __syncthreads();
}

// ---------------- encoder: 80 LSTM steps, block bk owns hidden units {2bk,2bk+1} ----------------
__global__ __launch_bounds__(256) void k_enc(const float* __restrict__ xg,   // [B*T,2048] (+both biases)
                                             const float* __restrict__ whh,  // [2048,512]
                                             float* __restrict__ hA, float* __restrict__ hB,
                                             float* __restrict__ cfin,
                                             float* __restrict__ encf,        // [b][t][512]
                                             unsigned short* __restrict__ encbf,
                                             int* __restrict__ flags, int* __restrict__ gen) {
  __shared__ __align__(16) float wsm[8 * 512];
  __shared__ float gsm[8 * 64];
  const int tid = threadIdx.x;
  const int u0 = blockIdx.x * 2;
  for (int idx = tid; idx < 8 * 512; idx += 256) {
    int r = idx >> 9, k = idx & 511;
    wsm[idx] = whh[(size_t)((r >> 1) * 512 + u0 + (r & 1)) * 512 + k];
  }
  __syncthreads();

  const int b = tid & 63, g = tid >> 6;
  const int uu2 = (tid >> 6) & 1;
  float cst = 0.f;
  int ph = 0;

  for (int t = 0; t < T_; ++t) {
    const float* hR = (t & 1) ? hB : hA;
    float* hW = (t & 1) ? hA : hB;
    float s0 = 0.f, s1 = 0.f;
    const f32x4* hv = (const f32x4*)(hR + b * 512);
    const f32x4* w0 = (const f32x4*)(wsm + (g * 2 + 0) * 512);
    const f32x4* w1 = (const f32x4*)(wsm + (g * 2 + 1) * 512);
#pragma unroll 8
    for (int k4 = 0; k4 < 128; ++k4) {
      f32x4 h4 = hv[k4], a4 = w0[k4], b4 = w1[k4];
      s0 += h4[0] * a4[0] + h4[1] * a4[1] + h4[2] * a4[2] + h4[3] * a4[3];
      s1 += h4[0] * b4[0] + h4[1] * b4[1] + h4[2] * b4[2] + h4[3] * b4[3];
    }
    size_t xoff = ((size_t)b * T_ + t) * 2048 + g * 512 + u0;
    gsm[(g * 2 + 0) * 64 + b] = s0 + xg[xoff];
    gsm[(g * 2 + 1) * 64 + b] = s1 + xg[xoff + 1];
    __syncthreads();
    if (tid < 128) {
      float iv = gsm[(0 + uu2) * 64 + b];
      float fv = gsm[(2 + uu2) * 64 + b];
      float gv = gsm[(4 + uu2) * 64 + b];
      float ov = gsm[(6 + uu2) * 64 + b];
      cst = sigmoidf(fv) * cst + sigmoidf(iv) * tanh_fast(gv);
      float hvv = sigmoidf(ov) * tanh_fast(cst);
      int u = u0 + uu2;
      hW[b * 512 + u] = hvv;
      encf[((size_t)b * T_ + t) * 512 + u] = hvv;
      encbf[((size_t)b * T_ + t) * 512 + u] = f2bf(hvv);
      if (t == T_ - 1) cfin[b * 512 + u] = cst;
    }
    gbar(flags, gen, gridDim.x, ++ph);
  }
}

// ---------------- decoder: 30 steps x {A: hW, B: attn+softmax+ctx, C: gates+LSTM} ----------------
__global__ __launch_bounds__(256) void k_dec(const float* __restrict__ attnw,  // [512][1024]
                                             const float* __restrict__ vw,
                                             const float* __restrict__ dwih,   // [2048][1024]
                                             const float* __restrict__ dwhh,   // [2048][512]
                                             const float* __restrict__ egates, // [1920][2048]
                                             const float* __restrict__ encpart,// [B*T][512]
                                             const float* __restrict__ encf,   // [b][t][512]
                                             const float* __restrict__ cfin,
                                             float* __restrict__ hA, float* __restrict__ hB,
                                             float* __restrict__ hWbuf, float* __restrict__ ctxbuf,
                                             unsigned short* __restrict__ hsbf,
                                             int* __restrict__ flags, int* __restrict__ gen) {
  __shared__ __align__(16) float wih2[8 * 512];
  __shared__ __align__(16) float whh[8 * 512];
  __shared__ __align__(16) float wa[2 * 512];
  __shared__ __align__(16) float vsm[512];
  __shared__ __align__(16) float hwb[512];
  __shared__ float ssm[128];
  __shared__ float gsm[8 * 64];
  const int tid = threadIdx.x;
  const int bk = blockIdx.x;
  const int u0 = bk * 2;
  for (int idx = tid; idx < 8 * 512; idx += 256) {
    int r = idx >> 9, k = idx & 511;
    int row = (r >> 1) * 512 + u0 + (r & 1);
    wih2[idx] = dwih[(size_t)row * 1024 + 512 + k];
    whh[idx] = dwhh[(size_t)row * 512 + k];
  }
  for (int idx = tid; idx < 2 * 512; idx += 256)
    wa[idx] = attnw[(size_t)(u0 + (idx >> 9)) * 1024 + (idx & 511)];
  for (int idx = tid; idx < 512; idx += 256) vsm[idx] = vw[idx];
  __syncthreads();

  const int b = tid & 63, g = tid >> 6;
  const int uu2 = (tid >> 6) & 1;
  float cst = 0.f;
  if (tid < 128) cst = cfin[b * 512 + u0 + uu2];
  int ph = 0;

  for (int l = 0; l < NDEC; ++l) {
    const float* hR = (l & 1) ? hB : hA;
    float* hN = (l & 1) ? hA : hB;
    // Phase A: hW[b, u0+uu] = h . Wa_h[u0+uu]
    if (tid < 128) {
      float s = 0.f;
      const f32x4* hv = (const f32x4*)(hR + b * 512);
      const f32x4* wv = (const f32x4*)(wa + uu2 * 512);
#pragma unroll 8
      for (int k4 = 0; k4 < 128; ++k4) {
        f32x4 h4 = hv[k4], w4 = wv[k4];
        s += h4[0] * w4[0] + h4[1] * w4[1] + h4[2] * w4[2] + h4[3] * w4[3];
      }
      hWbuf[b * 512 + u0 + uu2] = s;
    }
    gbar(flags, gen, gridDim.x, ++ph);
    // Phase B (blocks 0..63): scores, softmax, ctx for batch row bk
    if (bk < 64) {
      const int bb = bk;
      for (int idx = tid; idx < 512; idx += 256) hwb[idx] = hWbuf[bb * 512 + idx];
      __syncthreads();
      const int wv_ = tid >> 6, ln = tid & 63;
      for (int ti = wv_; ti < T_; ti += 4) {
        const float* ep = encpart + ((size_t)bb * T_ + ti) * 512 + ln * 8;
        float p = 0.f;
#pragma unroll
        for (int j = 0; j < 8; ++j)
          p += vsm[ln * 8 + j] * tanh_fast(hwb[ln * 8 + j] + ep[j]);
#pragma unroll
        for (int m = 1; m < 64; m <<= 1) p += __shfl_xor(p, m, 64);
        if (ln == 0) ssm[ti] = p;
      }
      __syncthreads();
      if (tid < 64) {
        float x0 = ssm[tid];
        float x1 = (tid < T_ - 64) ? ssm[64 + tid] : -1e30f;
        float mx = fmaxf(x0, x1);
#pragma unroll
        for (int m = 1; m < 64; m <<= 1) mx = fmaxf(mx, __shfl_xor(mx, m, 64));
        float e0 = __expf(x0 - mx);
        float e1 = (tid < T_ - 64) ? __expf(x1 - mx) : 0.f;
        float sm = e0 + e1;
#pragma unroll
        for (int m = 1; m < 64; m <<= 1) sm += __shfl_xor(sm, m, 64);
        ssm[tid] = e0 / sm;
        if (tid < T_ - 64) ssm[64 + tid] = e1 / sm;
      }
      __syncthreads();
      float a0 = 0.f, a1 = 0.f;
      const float* eb = encf + (size_t)bb * T_ * 512;
      for (int ti = 0; ti < T_; ++ti) {
        float w = ssm[ti];
        a0 += w * eb[ti * 512 + tid];
        a1 += w * eb[ti * 512 + 256 + tid];
      }
      ctxbuf[bb * 512 + tid] = a0;
      ctxbuf[bb * 512 + 256 + tid] = a1;
    }
    gbar(flags, gen, gridDim.x, ++ph);
    // Phase C: gates + LSTM pointwise
    {
      float s0 = 0.f, s1 = 0.f;
      const f32x4* cv = (const f32x4*)(ctxbuf + b * 512);
      const f32x4* hv = (const f32x4*)(hR + b * 512);
      const f32x4* wi0 = (const f32x4*)(wih2 + (g * 2 + 0) * 512);
      const f32x4* wi1 = (const f32x4*)(wih2 + (g * 2 + 1) * 512);
      const f32x4* wh0 = (const f32x4*)(whh + (g * 2 + 0) * 512);
      const f32x4* wh1 = (const f32x4*)(whh + (g * 2 + 1) * 512);
#pragma unroll 4
      for (int k4 = 0; k4 < 128; ++k4) {
        f32x4 c4 = cv[k4], h4 = hv[k4];
        f32x4 x0 = wi0[k4], x1 = wi1[k4], y0 = wh0[k4], y1 = wh1[k4];
        s0 += c4[0] * x0[0] + c4[1] * x0[1] + c4[2] * x0[2] + c4[3] * x0[3]
            + h4[0] * y0[0] + h4[1] * y0[1] + h4[2] * y0[2] + h4[3] * y0[3];
        s1 += c4[0] * x1[0] + c4[1] * x1[1] + c4[2] * x1[2] + c4[3] * x1[3]
            + h4[0] * y1[0] + h4[1] * y1[1] + h4[2] * y1[2] + h4[3] * y1[3];
      }
      size_t eoff = ((size_t)l * 64 + b) * 2048 + g * 512 + u0;
      gsm[(g * 2 + 0) * 64 + b] = s0 + egates[eoff];
      gsm[(g * 2 + 1) * 64 + b] = s1 + egates[eoff + 1];
    }
    __syncthreads();
    if (tid < 128) {
      float iv = gsm[(0 + uu2) * 64 + b];
      float fv = gsm[(2 + uu2) * 64 + b];
      float gv = gsm[(4 + uu2) * 64 + b];
      float ov = gsm[(6 + uu2) * 64 + b];
      cst = sigmoidf(fv) * cst + sigmoidf(iv) * tanh_fast(gv);
      float hvv = sigmoidf(ov) * tanh_fast(cst);
      int u = u0 + uu2;
      hN[b * 512 + u] = hvv;
      hsbf[((size_t)l * 64 + b) * 512 + u] = f2bf(hvv);
    }
    gbar(flags, gen, gridDim.x, ++ph);
  }
}

// ---------------- launch ----------------
extern "C" void kernel_launch(void* const* d_in, const int* in_sizes, int n_in,
                              void* d_out, int out_size, void* d_ws, size_t ws_size,
                              hipStream_t stream) {
  const float* video = (const float*)d_in[0];
  const int* captions = (const int*)d_in[1];
  const float* emb = (const float*)d_in[2];
  const float* eWih = (const float*)d_in[3];
  const float* eWhh = (const float*)d_in[4];
  const float* ebih = (const float*)d_in[5];
  const float* ebhh = (const float*)d_in[6];
  const float* attnW = (const float*)d_in[7];
  const float* attnb = (const float*)d_in[8];
  const float* vw = (const float*)d_in[9];
  const float* dWih = (const float*)d_in[10];
  const float* dWhh = (const float*)d_in[11];
  const float* dbih = (const float*)d_in[12];
  const float* dbhh = (const float*)d_in[13];
  const float* fcW = (const float*)d_in[14];
  const float* fcb = (const float*)d_in[15];

  char* ws = (char*)d_ws;
  unsigned short* vid_bf = (unsigned short*)(ws + 0);           // 41,943,040 B (dead after K1)
  unsigned short* fcw_bf = (unsigned short*)(ws + 0);           // 32,768,000 B (after K1)
  unsigned short* hs_bf = (unsigned short*)(ws + 33554432ull);  // 1,966,080 B
  float* xg = (float*)(ws + 41943040ull);                       // 41,943,040 B (dead after enc)
  float* encpart = (float*)(ws + 41943040ull);                  // 10,485,760 B (after enc)
  float* egates = (float*)(ws + 52428800ull);                   // 15,728,640 B (after enc)
  unsigned short* aemb = (unsigned short*)(ws + 68157440ull);   // 1,966,080 B (after enc)
  unsigned short* ewih_bf = (unsigned short*)(ws + 83886080ull);// 16,777,216 B
  float* encf = (float*)(ws + 100663296ull);                    // 10,485,760 B
  unsigned short* encbf = (unsigned short*)(ws + 111149056ull); // 5,242,880 B
  unsigned short* attnw_bf = (unsigned short*)(ws + 116391936ull); // 1,048,576 B
  unsigned short* dwih_bf = (unsigned short*)(ws + 117440512ull);  // 4,194,304 B
  float* hA = (float*)(ws + 121634816ull);
  float* hB = (float*)(ws + 121765888ull);
  float* cfin = (float*)(ws + 121896960ull);
  float* hWbuf = (float*)(ws + 122028032ull);
  float* ctxbuf = (float*)(ws + 122159104ull);
  int* barEf = (int*)(ws + 122290176ull);   // 256 ints
  int* barEg = (int*)(ws + 122291200ull);   // own line
  int* barDf = (int*)(ws + 122291456ull);   // 256 ints
  int* barDg = (int*)(ws + 122292480ull);   // own line
  int* flag = (int*)(ws + 122292736ull);

  hipMemsetAsync(ws + 121634816ull, 0, 122292992ull - 121634816ull, stream);

  auto cvt = [&](const float* in, unsigned short* out, long n) {
    long n4 = n / 4;
    int blocks = (int)((n4 + 255) / 256);
    if (blocks > 2048) blocks = 2048;
    k_cvt<<<blocks, 256, 0, stream>>>(in, out, n4);
  };
  cvt(video, vid_bf, 5120L * 4096);
  cvt(eWih, ewih_bf, 2048L * 4096);
  cvt(attnW, attnw_bf, 512L * 1024);
  cvt(dWih, dwih_bf, 2048L * 1024);
  k_detect_i64<<<1, 256, 0, stream>>>(captions, flag);

  // K1: X_gates = video @ enc_Wih^T + ebih + ebhh   [5120 x 2048]
  k_gemm<0><<<dim3(16, 40), 256, 0, stream>>>(vid_bf, 4096, ewih_bf, 4096, xg, 2048, 4096, ebih, ebhh);
  cvt(fcW, fcw_bf, 32000L * 512);

  k_enc<<<256, 256, 0, stream>>>(xg, eWhh, hA, hB, cfin, encf, encbf, barEf, barEg);

  k_gather_emb<<<1920, 256, 0, stream>>>(emb, captions, flag, aemb);
  // EncPart = enc_out @ attn_W[:,512:]^T + attn_b   [5120 x 512]
  k_gemm<0><<<dim3(4, 40), 256, 0, stream>>>(encbf, 512, attnw_bf + 512, 1024, encpart, 512, 512, attnb, nullptr);
  // E_gates = emb[tok] @ dec_Wih[:,:512]^T + dbih + dbhh   [1920 x 2048]
  k_gemm<0><<<dim3(16, 15), 256, 0, stream>>>(aemb, 512, dwih_bf, 1024, egates, 2048, 512, dbih, dbhh);

  k_dec<<<256, 256, 0, stream>>>(attnW, vw, dWih, dWhh, egates, encpart, encf, cfin,
                                 hA, hB, hWbuf, ctxbuf, hs_bf, barDf, barDg);

  // FC: out[b][l][v] = Hs @ fc_W^T + fc_b   [1920 x 32000]
  k_gemm<1><<<dim3(250, 15), 256, 0, stream>>>(hs_bf, 512, fcw_bf, 512, (float*)d_out, 32000, 512, fcb, nullptr);
}

// Round 4
// 4441.742 us; speedup vs baseline: 2.5823x; 1.2514x over previous
//
#include <hip/hip_runtime.h>

// S2VT + attention, decomposed:
//  1. cvt fp32->bf16 (video, enc_Wih, attn_W, dec_Wih, fc_W)
//  2. K1 GEMM: X_gates[b*80+t, 2048] = video @ enc_Wih^T + bih + bhh   (bf16 MFMA)
//  3. k_enc persistent: 80 LSTM steps, grid barrier per step; writes enc_out (f32+bf16), final h,c
//  4. EncPart GEMM: enc_out @ attn_W[:,512:]^T + attn_b
//     E_gates GEMM: emb[tok] @ dec_Wih[:,:512]^T + dbih + dbhh
//  5. k_dec persistent: 30 steps x {hW, attention+softmax+ctx, gates+LSTM}; writes Hs bf16
//  6. FC GEMM: Hs @ fc_W^T + fc_b -> out[b][l][v]   (bf16 MFMA)
//
// Barrier history: R1 per-poll ACQUIRE invalidates (79us/bar). R2 relaxed polls
// (41.7us/bar, RMW serialization). R3 flags array (31.7us/bar; residual =
// per-block release wbl2 + 255-blocks-poll-one-line wake contention).
// R4: (a) shared data written via relaxed AGENT atomic stores (sc0+sc1
// write-through -> no wbl2 release needed; __syncthreads drains vmcnt),
// (b) padded per-block flag lines, (c) fan-out wake: block0 stores gen to 256
// distinct lines, each waiter polls its OWN line. Only remaining cache op:
// one acquire fence (buffer_inv, no writeback) per block per barrier, needed
// for plain cached reads of broadcast buffers.

#define DEV __device__ __forceinline__

typedef __attribute__((ext_vector_type(4))) float f32x4;
typedef __attribute__((ext_vector_type(8))) short bf16x8;

static constexpr int B_ = 64, T_ = 80, H_ = 512, L_ = 31, NDEC = 30;

DEV unsigned short f2bf(float f) {
  unsigned u = __builtin_bit_cast(unsigned, f);
  u += 0x7FFF + ((u >> 16) & 1);
  return (unsigned short)(u >> 16);
}
DEV float sigmoidf(float x) { return 1.f / (1.f + __expf(-x)); }
DEV float tanh_fast(float x) { float e = __expf(2.f * x); return (e - 1.f) / (e + 1.f); }

// agent-visible write-through store (no release/wbl2 needed at barrier)
DEV void stg(float* p, float v) {
  __hip_atomic_store(p, v, __ATOMIC_RELAXED, __HIP_MEMORY_SCOPE_AGENT);
}

// ---------------- fp32 -> bf16 convert ----------------
__global__ __launch_bounds__(256) void k_cvt(const float* __restrict__ in,
                                             unsigned short* __restrict__ out, long n4) {
  long i = (long)blockIdx.x * 256 + threadIdx.x;
  long stride = (long)gridDim.x * 256;
  for (; i < n4; i += stride) {
    float4 v = reinterpret_cast<const float4*>(in)[i];
    ushort4 o;
    o.x = f2bf(v.x); o.y = f2bf(v.y); o.z = f2bf(v.z); o.w = f2bf(v.w);
    reinterpret_cast<ushort4*>(out)[i] = o;
  }
}

// ---------------- int64-vs-int32 caption detect ----------------
__global__ void k_detect_i64(const int* __restrict__ cap, int* __restrict__ flag) {
  __shared__ int s;
  if (threadIdx.x == 0) s = 0;
  __syncthreads();
  int acc = 0;
  for (int i = threadIdx.x; i < (B_ * L_) / 2; i += 256) acc |= cap[2 * i + 1];
  if (acc) atomicOr(&s, 1);
  __syncthreads();
  if (threadIdx.x == 0) flag[0] = (s == 0) ? 1 : 0;  // all-high-words-zero => int64
}

// ---------------- embedding gather (rows r = l*64+b) ----------------
__global__ __launch_bounds__(256) void k_gather_emb(const float* __restrict__ emb,
                                                    const int* __restrict__ cap,
                                                    const int* __restrict__ flag,
                                                    unsigned short* __restrict__ aemb) {
  int r = blockIdx.x;            // 0..1919
  int l = r >> 6, b = r & 63;
  int ci = b * L_ + l;
  int tok = flag[0] ? cap[2 * ci] : cap[ci];
  const float* src = emb + (size_t)tok * H_;
  unsigned short* dst = aemb + (size_t)r * H_;
  for (int c = threadIdx.x; c < H_; c += 256) dst[c] = f2bf(src[c]);
}

// ---------------- bf16 MFMA GEMM: C[M,N] = A[M,K] * B[N,K]^T + bias ----------------
// 128x128 tile, BK=32, 4 waves (each 64x64 = 4x4 fragments of 16x16x32).
// LDS row pitch 40 shorts (80B) to break the 64B-stride bank conflict.
template <int OUT_MODE>  // 0: row-major ldc=N ; 1: row r=(l*64+b) -> out[(b*30+l)*N + col]
__global__ __launch_bounds__(256) void k_gemm(const unsigned short* __restrict__ A, int lda,
                                              const unsigned short* __restrict__ Bm, int ldb,
                                              float* __restrict__ C, int N, int K,
                                              const float* __restrict__ bias0,
                                              const float* __restrict__ bias1) {
  __shared__ __align__(16) unsigned short As[128 * 40];
  __shared__ __align__(16) unsigned short Bs[128 * 40];
  const int tid = threadIdx.x;
  const int m0 = blockIdx.y * 128, n0 = blockIdx.x * 128;
  const int wave = tid >> 6, lane = tid & 63;
  const int wm = wave >> 1, wn = wave & 1;
  const int lr = lane & 15, lk = lane >> 4;

  f32x4 acc[4][4];
#pragma unroll
  for (int m = 0; m < 4; ++m)
#pragma unroll
    for (int n = 0; n < 4; ++n) acc[m][n] = (f32x4){0.f, 0.f, 0.f, 0.f};

  const int c0 = tid, c1 = tid + 256;
  const int ar0 = c0 >> 2, as0 = c0 & 3;
  const int ar1 = c1 >> 2, as1 = c1 & 3;

  for (int k0 = 0; k0 < K; k0 += 32) {
    uint4 va0 = *(const uint4*)(A + (size_t)(m0 + ar0) * lda + k0 + as0 * 8);
    uint4 va1 = *(const uint4*)(A + (size_t)(m0 + ar1) * lda + k0 + as1 * 8);
    uint4 vb0 = *(const uint4*)(Bm + (size_t)(n0 + ar0) * ldb + k0 + as0 * 8);
    uint4 vb1 = *(const uint4*)(Bm + (size_t)(n0 + ar1) * ldb + k0 + as1 * 8);
    *(uint4*)(As + ar0 * 40 + as0 * 8) = va0;
    *(uint4*)(As + ar1 * 40 + as1 * 8) = va1;
    *(uint4*)(Bs + ar0 * 40 + as0 * 8) = vb0;
    *(uint4*)(Bs + ar1 * 40 + as1 * 8) = vb1;
    __syncthreads();
    bf16x8 af[4], bfr[4];
#pragma unroll
    for (int m = 0; m < 4; ++m)
      af[m] = *(const bf16x8*)(As + (wm * 64 + m * 16 + lr) * 40 + lk * 8);
#pragma unroll
    for (int n = 0; n < 4; ++n)
      bfr[n] = *(const bf16x8*)(Bs + (wn * 64 + n * 16 + lr) * 40 + lk * 8);
#pragma unroll
    for (int m = 0; m < 4; ++m)
#pragma unroll
      for (int n = 0; n < 4; ++n)
        acc[m][n] = __builtin_amdgcn_mfma_f32_16x16x32_bf16(af[m], bfr[n], acc[m][n], 0, 0, 0);
    __syncthreads();
  }
#pragma unroll
  for (int m = 0; m < 4; ++m) {
#pragma unroll
    for (int n = 0; n < 4; ++n) {
      const int col = n0 + wn * 64 + n * 16 + lr;
      float bv = (bias0 ? bias0[col] : 0.f) + (bias1 ? bias1[col] : 0.f);
#pragma unroll
      for (int j = 0; j < 4; ++j) {
        const int row = m0 + wm * 64 + m * 16 + lk * 4 + j;
        float v = acc[m][n][j] + bv;
        if (OUT_MODE == 0) {
          C[(size_t)row * N + col] = v;
        } else {
          int l = row >> 6, b = row & 63;
          C[((size_t)b * NDEC + l) * (size_t)N + col] = v;
        }
      }
    }
  }
}

// ---------------- grid barrier: padded flags, fan-out wake, no wbl2 ----------------
// flagsPad/genPad: one 64B line (16 ints) per block. ph monotonically increasing.
// Entry __syncthreads drains each wave's stores (sc1 write-through -> visible at L3),
// so relaxed flag stores are a correct release. One acquire fence (buffer_inv) per
// block on exit keeps plain cached reads of broadcast buffers coherent.
DEV void gbar(int* __restrict__ flagsPad, int* __restrict__ genPad, int nb, int ph) {
  __syncthreads();
  const int tid = threadIdx.x;
  if (blockIdx.x == 0) {
    if (tid > 0 && tid < nb)
      while (__hip_atomic_load(flagsPad + tid * 16, __ATOMIC_RELAXED, __HIP_MEMORY_SCOPE_AGENT) < ph)
        __builtin_amdgcn_s_sleep(1);
    __syncthreads();
    if (tid < nb)
      __hip_atomic_store(genPad + tid * 16, ph, __ATOMIC_RELAXED, __HIP_MEMORY_SCOPE_AGENT);
    if (tid == 0) __builtin_amdgcn_fence(__ATOMIC_ACQUIRE, "agent");
  } else {
    if (tid == 0) {
      __hip_atomic_store(flagsPad + blockIdx.x * 16, ph, __ATOMIC_RELAXED, __HIP_MEMORY_SCOPE_AGENT);
      while (__hip_atomic_load(genPad + blockIdx.x * 16, __ATOMIC_RELAXED, __HIP_MEMORY_SCOPE_AGENT) < ph)
        __builtin_amdgcn_s_sleep(1);
      __builtin_amdgcn_fence(__ATOMIC_ACQUIRE, "agent");
    }
  }
  __syncthreads();
}

// ---------------- encoder: 80 LSTM steps, block bk owns hidden units {2bk,2bk+1} ----------------
__global__ __launch_bounds__(256) void k_enc(const float* __restrict__ xg,   // [B*T,2048] (+both biases)
                                             const float* __restrict__ whh,  // [2048,512]
                                             float* __restrict__ hA, float* __restrict__ hB,
                                             float* __restrict__ cfin,
                                             float* __restrict__ encf,        // [b][t][512]
                                             unsigned short* __restrict__ encbf,
                                             int* __restrict__ flags, int* __restrict__ gen) {
  __shared__ __align__(16) float wsm[8 * 512];
  __shared__ float gsm[8 * 64];
  const int tid = threadIdx.x;
  const int u0 = blockIdx.x * 2;
  for (int idx = tid; idx < 8 * 512; idx += 256) {
    int r = idx >> 9, k = idx & 511;
    wsm[idx] = whh[(size_t)((r >> 1) * 512 + u0 + (r & 1)) * 512 + k];
  }
  __syncthreads();

  const int b = tid & 63, g = tid >> 6;
  const int uu2 = (tid >> 6) & 1;
  float cst = 0.f;
  int ph = 0;

  for (int t = 0; t < T_; ++t) {
    const float* hR = (t & 1) ? hB : hA;
    float* hW = (t & 1) ? hA : hB;
    float s0 = 0.f, s1 = 0.f;
    const f32x4* hv = (const f32x4*)(hR + b * 512);
    const f32x4* w0 = (const f32x4*)(wsm + (g * 2 + 0) * 512);
    const f32x4* w1 = (const f32x4*)(wsm + (g * 2 + 1) * 512);
#pragma unroll 8
    for (int k4 = 0; k4 < 128; ++k4) {
      f32x4 h4 = hv[k4], a4 = w0[k4], b4 = w1[k4];
      s0 += h4[0] * a4[0] + h4[1] * a4[1] + h4[2] * a4[2] + h4[3] * a4[3];
      s1 += h4[0] * b4[0] + h4[1] * b4[1] + h4[2] * b4[2] + h4[3] * b4[3];
    }
    size_t xoff = ((size_t)b * T_ + t) * 2048 + g * 512 + u0;
    gsm[(g * 2 + 0) * 64 + b] = s0 + xg[xoff];
    gsm[(g * 2 + 1) * 64 + b] = s1 + xg[xoff + 1];
    __syncthreads();
    if (tid < 128) {
      float iv = gsm[(0 + uu2) * 64 + b];
      float fv = gsm[(2 + uu2) * 64 + b];
      float gv = gsm[(4 + uu2) * 64 + b];
      float ov = gsm[(6 + uu2) * 64 + b];
      cst = sigmoidf(fv) * cst + sigmoidf(iv) * tanh_fast(gv);
      float hvv = sigmoidf(ov) * tanh_fast(cst);
      int u = u0 + uu2;
      stg(hW + b * 512 + u, hvv);
      encf[((size_t)b * T_ + t) * 512 + u] = hvv;
      encbf[((size_t)b * T_ + t) * 512 + u] = f2bf(hvv);
      if (t == T_ - 1) cfin[b * 512 + u] = cst;
    }
    gbar(flags, gen, gridDim.x, ++ph);
  }
}

// ---------------- decoder: 30 steps x {A: hW, B: attn+softmax+ctx, C: gates+LSTM} ----------------
__global__ __launch_bounds__(256) void k_dec(const float* __restrict__ attnw,  // [512][1024]
                                             const float* __restrict__ vw,
                                             const float* __restrict__ dwih,   // [2048][1024]
                                             const float* __restrict__ dwhh,   // [2048][512]
                                             const float* __restrict__ egates, // [1920][2048]
                                             const float* __restrict__ encpart,// [B*T][512]
                                             const float* __restrict__ encf,   // [b][t][512]
                                             const float* __restrict__ cfin,
                                             float* __restrict__ hA, float* __restrict__ hB,
                                             float* __restrict__ hWbuf, float* __restrict__ ctxbuf,
                                             unsigned short* __restrict__ hsbf,
                                             int* __restrict__ flags, int* __restrict__ gen) {
  __shared__ __align__(16) float wih2[8 * 512];
  __shared__ __align__(16) float whh[8 * 512];
  __shared__ __align__(16) float wa[2 * 512];
  __shared__ __align__(16) float vsm[512];
  __shared__ __align__(16) float hwb[512];
  __shared__ float ssm[128];
  __shared__ float gsm[8 * 64];
  const int tid = threadIdx.x;
  const int bk = blockIdx.x;
  const int u0 = bk * 2;
  for (int idx = tid; idx < 8 * 512; idx += 256) {
    int r = idx >> 9, k = idx & 511;
    int row = (r >> 1) * 512 + u0 + (r & 1);
    wih2[idx] = dwih[(size_t)row * 1024 + 512 + k];
    whh[idx] = dwhh[(size_t)row * 512 + k];
  }
  for (int idx = tid; idx < 2 * 512; idx += 256)
    wa[idx] = attnw[(size_t)(u0 + (idx >> 9)) * 1024 + (idx & 511)];
  for (int idx = tid; idx < 512; idx += 256) vsm[idx] = vw[idx];
  __syncthreads();

  const int b = tid & 63, g = tid >> 6;
  const int uu2 = (tid >> 6) & 1;
  float cst = 0.f;
  if (tid < 128) cst = cfin[b * 512 + u0 + uu2];
  int ph = 0;

  for (int l = 0; l < NDEC; ++l) {
    const float* hR = (l & 1) ? hB : hA;
    float* hN = (l & 1) ? hA : hB;
    // Phase A: hW[b, u0+uu] = h . Wa_h[u0+uu]
    if (tid < 128) {
      float s = 0.f;
      const f32x4* hv = (const f32x4*)(hR + b * 512);
      const f32x4* wv = (const f32x4*)(wa + uu2 * 512);
#pragma unroll 8
      for (int k4 = 0; k4 < 128; ++k4) {
        f32x4 h4 = hv[k4], w4 = wv[k4];
        s += h4[0] * w4[0] + h4[1] * w4[1] + h4[2] * w4[2] + h4[3] * w4[3];
      }
      stg(hWbuf + b * 512 + u0 + uu2, s);
    }
    gbar(flags, gen, gridDim.x, ++ph);
    // Phase B (blocks 0..63): scores, softmax, ctx for batch row bk
    if (bk < 64) {
      const int bb = bk;
      for (int idx = tid; idx < 512; idx += 256) hwb[idx] = hWbuf[bb * 512 + idx];
      __syncthreads();
      const int wv_ = tid >> 6, ln = tid & 63;
      for (int ti = wv_; ti < T_; ti += 4) {
        const float* ep = encpart + ((size_t)bb * T_ + ti) * 512 + ln * 8;
        float p = 0.f;
#pragma unroll
        for (int j = 0; j < 8; ++j)
          p += vsm[ln * 8 + j] * tanh_fast(hwb[ln * 8 + j] + ep[j]);
#pragma unroll
        for (int m = 1; m < 64; m <<= 1) p += __shfl_xor(p, m, 64);
        if (ln == 0) ssm[ti] = p;
      }
      __syncthreads();
      if (tid < 64) {
        float x0 = ssm[tid];
        float x1 = (tid < T_ - 64) ? ssm[64 + tid] : -1e30f;
        float mx = fmaxf(x0, x1);
#pragma unroll
        for (int m = 1; m < 64; m <<= 1) mx = fmaxf(mx, __shfl_xor(mx, m, 64));
        float e0 = __expf(x0 - mx);
        float e1 = (tid < T_ - 64) ? __expf(x1 - mx) : 0.f;
        float sm = e0 + e1;
#pragma unroll
        for (int m = 1; m < 64; m <<= 1) sm += __shfl_xor(sm, m, 64);
        ssm[tid] = e0 / sm;
        if (tid < T_ - 64) ssm[64 + tid] = e1 / sm;
      }
      __syncthreads();
      float a0 = 0.f, a1 = 0.f;
      const float* eb = encf + (size_t)bb * T_ * 512;
      for (int ti = 0; ti < T_; ++ti) {
        float w = ssm[ti];
        a0 += w * eb[ti * 512 + tid];
        a1 += w * eb[ti * 512 + 256 + tid];
      }
      stg(ctxbuf + bb * 512 + tid, a0);
      stg(ctxbuf + bb * 512 + 256 + tid, a1);
    }
    gbar(flags, gen, gridDim.x, ++ph);
    // Phase C: gates + LSTM pointwise
    {
      float s0 = 0.f, s1 = 0.f;
      const f32x4* cv = (const f32x4*)(ctxbuf + b * 512);
      const f32x4* hv = (const f32x4*)(hR + b * 512);
      const f32x4* wi0 = (const f32x4*)(wih2 + (g * 2 + 0) * 512);
      const f32x4* wi1 = (const f32x4*)(wih2 + (g * 2 + 1) * 512);
      const f32x4* wh0 = (const f32x4*)(whh + (g * 2 + 0) * 512);
      const f32x4* wh1 = (const f32x4*)(whh + (g * 2 + 1) * 512);
#pragma unroll 4
      for (int k4 = 0; k4 < 128; ++k4) {
        f32x4 c4 = cv[k4], h4 = hv[k4];
        f32x4 x0 = wi0[k4], x1 = wi1[k4], y0 = wh0[k4], y1 = wh1[k4];
        s0 += c4[0] * x0[0] + c4[1] * x0[1] + c4[2] * x0[2] + c4[3] * x0[3]
            + h4[0] * y0[0] + h4[1] * y0[1] + h4[2] * y0[2] + h4[3] * y0[3];
        s1 += c4[0] * x1[0] + c4[1] * x1[1] + c4[2] * x1[2] + c4[3] * x1[3]
            + h4[0] * y1[0] + h4[1] * y1[1] + h4[2] * y1[2] + h4[3] * y1[3];
      }
      size_t eoff = ((size_t)l * 64 + b) * 2048 + g * 512 + u0;
      gsm[(g * 2 + 0) * 64 + b] = s0 + egates[eoff];
      gsm[(g * 2 + 1) * 64 + b] = s1 + egates[eoff + 1];
    }
    __syncthreads();
    if (tid < 128) {
      float iv = gsm[(0 + uu2) * 64 + b];
      float fv = gsm[(2 + uu2) * 64 + b];
      float gv = gsm[(4 + uu2) * 64 + b];
      float ov = gsm[(6 + uu2) * 64 + b];
      cst = sigmoidf(fv) * cst + sigmoidf(iv) * tanh_fast(gv);
      float hvv = sigmoidf(ov) * tanh_fast(cst);
      int u = u0 + uu2;
      stg(hN + b * 512 + u, hvv);
      hsbf[((size_t)l * 64 + b) * 512 + u] = f2bf(hvv);
    }
    gbar(flags, gen, gridDim.x, ++ph);
  }
}

// ---------------- launch ----------------
extern "C" void kernel_launch(void* const* d_in, const int* in_sizes, int n_in,
                              void* d_out, int out_size, void* d_ws, size_t ws_size,
                              hipStream_t stream) {
  const float* video = (const float*)d_in[0];
  const int* captions = (const int*)d_in[1];
  const float* emb = (const float*)d_in[2];
  const float* eWih = (const float*)d_in[3];
  const float* eWhh = (const float*)d_in[4];
  const float* ebih = (const float*)d_in[5];
  const float* ebhh = (const float*)d_in[6];
  const float* attnW = (const float*)d_in[7];
  const float* attnb = (const float*)d_in[8];
  const float* vw = (const float*)d_in[9];
  const float* dWih = (const float*)d_in[10];
  const float* dWhh = (const float*)d_in[11];
  const float* dbih = (const float*)d_in[12];
  const float* dbhh = (const float*)d_in[13];
  const float* fcW = (const float*)d_in[14];
  const float* fcb = (const float*)d_in[15];

  char* ws = (char*)d_ws;
  unsigned short* vid_bf = (unsigned short*)(ws + 0);           // 41,943,040 B (dead after K1)
  unsigned short* fcw_bf = (unsigned short*)(ws + 0);           // 32,768,000 B (after K1)
  unsigned short* hs_bf = (unsigned short*)(ws + 33554432ull);  // 1,966,080 B
  float* xg = (float*)(ws + 41943040ull);                       // 41,943,040 B (dead after enc)
  float* encpart = (float*)(ws + 41943040ull);                  // 10,485,760 B (after enc)
  float* egates = (float*)(ws + 52428800ull);                   // 15,728,640 B (after enc)
  unsigned short* aemb = (unsigned short*)(ws + 68157440ull);   // 1,966,080 B (after enc)
  unsigned short* ewih_bf = (unsigned short*)(ws + 83886080ull);// 16,777,216 B
  float* encf = (float*)(ws + 100663296ull);                    // 10,485,760 B
  unsigned short* encbf = (unsigned short*)(ws + 111149056ull); // 5,242,880 B
  unsigned short* attnw_bf = (unsigned short*)(ws + 116391936ull); // 1,048,576 B
  unsigned short* dwih_bf = (unsigned short*)(ws + 117440512ull);  // 4,194,304 B
  float* hA = (float*)(ws + 121634816ull);
  float* hB = (float*)(ws + 121765888ull);
  float* cfin = (float*)(ws + 121896960ull);
  float* hWbuf = (float*)(ws + 122028032ull);
  float* ctxbuf = (float*)(ws + 122159104ull);
  int* barEf = (int*)(ws + 122290176ull);   // 256 x 64B padded lines
  int* barEg = (int*)(ws + 122306560ull);   // 256 x 64B padded lines
  int* barDf = (int*)(ws + 122322944ull);   // 256 x 64B padded lines
  int* barDg = (int*)(ws + 122339328ull);   // 256 x 64B padded lines
  int* flag = (int*)(ws + 122355712ull);

  hipMemsetAsync(ws + 121634816ull, 0, 122355716ull - 121634816ull, stream);

  auto cvt = [&](const float* in, unsigned short* out, long n) {
    long n4 = n / 4;
    int blocks = (int)((n4 + 255) / 256);
    if (blocks > 2048) blocks = 2048;
    k_cvt<<<blocks, 256, 0, stream>>>(in, out, n4);
  };
  cvt(video, vid_bf, 5120L * 4096);
  cvt(eWih, ewih_bf, 2048L * 4096);
  cvt(attnW, attnw_bf, 512L * 1024);
  cvt(dWih, dwih_bf, 2048L * 1024);
  k_detect_i64<<<1, 256, 0, stream>>>(captions, flag);

  // K1: X_gates = video @ enc_Wih^T + ebih + ebhh   [5120 x 2048]
  k_gemm<0><<<dim3(16, 40), 256, 0, stream>>>(vid_bf, 4096, ewih_bf, 4096, xg, 2048, 4096, ebih, ebhh);
  cvt(fcW, fcw_bf, 32000L * 512);

  k_enc<<<256, 256, 0, stream>>>(xg, eWhh, hA, hB, cfin, encf, encbf, barEf, barEg);

  k_gather_emb<<<1920, 256, 0, stream>>>(emb, captions, flag, aemb);
  // EncPart = enc_out @ attn_W[:,512:]^T + attn_b   [5120 x 512]
  k_gemm<0><<<dim3(4, 40), 256, 0, stream>>>(encbf, 512, attnw_bf + 512, 1024, encpart, 512, 512, attnb, nullptr);
  // E_gates = emb[tok] @ dec_Wih[:,:512]^T + dbih + dbhh   [1920 x 2048]
  k_gemm<0><<<dim3(16, 15), 256, 0, stream>>>(aemb, 512, dwih_bf, 1024, egates, 2048, 512, dbih, dbhh);

  k_dec<<<256, 256, 0, stream>>>(attnW, vw, dWih, dWhh, egates, encpart, encf, cfin,
                                 hA, hB, hWbuf, ctxbuf, hs_bf, barDf, barDg);

  // FC: out[b][l][v] = Hs @ fc_W^T + fc_b   [1920 x 32000]
  k_gemm<1><<<dim3(250, 15), 256, 0, stream>>>(hs_bf, 512, fcw_bf, 512, (float*)d_out, 32000, 512, fcb, nullptr);
}

// Round 5
// 3226.326 us; speedup vs baseline: 3.5551x; 1.3767x over previous
//
#include <hip/hip_runtime.h>

// S2VT + attention — R5: barrier-free batch-parallel recurrence.
//  Grid-barrier history: R1 79us/bar -> R4 27us/bar; structural floor too high.
//  New: one block per batch element (64 blocks x 512 threads), thread j owns
//  hidden unit j (gate rows j,512+j,1024+j,1536+j). h/c/attention all
//  block-local: NO grid barriers, NO fences, NO agent atomics.
//  Recurrent matvecs use f16 weights + v_dot2_f32_f16, packed [k2][j][4g] so
//  the inner loop is one coalesced dwordx4 per thread per k-pair.
//  GEMMs (bf16 MFMA): K1 (video@Wih, gate-packed out), EncPart, E_gates
//  (gate-packed out), FC. Pack kernels build f16 weight layouts once.

#define DEV __device__ __forceinline__

typedef __attribute__((ext_vector_type(4))) float f32x4;
typedef __attribute__((ext_vector_type(8))) short bf16x8;
typedef _Float16 half2_t __attribute__((ext_vector_type(2)));

static constexpr int B_ = 64, T_ = 80, H_ = 512, L_ = 31, NDEC = 30;

DEV unsigned short f2bf(float f) {
  unsigned u = __builtin_bit_cast(unsigned, f);
  u += 0x7FFF + ((u >> 16) & 1);
  return (unsigned short)(u >> 16);
}
DEV unsigned short f2h(float x) {
  return __builtin_bit_cast(unsigned short, (_Float16)x);
}
DEV unsigned f2h2(float lo, float hi) {
  return (unsigned)f2h(lo) | ((unsigned)f2h(hi) << 16);
}
DEV float fdot2(unsigned x, unsigned w, float acc) {
  return __builtin_amdgcn_fdot2(__builtin_bit_cast(half2_t, x),
                                __builtin_bit_cast(half2_t, w), acc, false);
}
DEV float sigmoidf(float x) { return 1.f / (1.f + __expf(-x)); }
DEV float tanh_fast(float x) { float e = __expf(2.f * x); return (e - 1.f) / (e + 1.f); }

// ---------------- fp32 -> bf16 convert ----------------
__global__ __launch_bounds__(256) void k_cvt(const float* __restrict__ in,
                                             unsigned short* __restrict__ out, long n4) {
  long i = (long)blockIdx.x * 256 + threadIdx.x;
  long stride = (long)gridDim.x * 256;
  for (; i < n4; i += stride) {
    float4 v = reinterpret_cast<const float4*>(in)[i];
    ushort4 o;
    o.x = f2bf(v.x); o.y = f2bf(v.y); o.z = f2bf(v.z); o.w = f2bf(v.w);
    reinterpret_cast<ushort4*>(out)[i] = o;
  }
}

// ---------------- int64-vs-int32 caption detect ----------------
__global__ void k_detect_i64(const int* __restrict__ cap, int* __restrict__ flag) {
  __shared__ int s;
  if (threadIdx.x == 0) s = 0;
  __syncthreads();
  int acc = 0;
  for (int i = threadIdx.x; i < (B_ * L_) / 2; i += 256) acc |= cap[2 * i + 1];
  if (acc) atomicOr(&s, 1);
  __syncthreads();
  if (threadIdx.x == 0) flag[0] = (s == 0) ? 1 : 0;  // all-high-words-zero => int64
}

// ---------------- embedding gather (rows r = l*64+b) ----------------
__global__ __launch_bounds__(256) void k_gather_emb(const float* __restrict__ emb,
                                                    const int* __restrict__ cap,
                                                    const int* __restrict__ flag,
                                                    unsigned short* __restrict__ aemb) {
  int r = blockIdx.x;            // 0..1919
  int l = r >> 6, b = r & 63;
  int ci = b * L_ + l;
  int tok = flag[0] ? cap[2 * ci] : cap[ci];
  const float* src = emb + (size_t)tok * H_;
  unsigned short* dst = aemb + (size_t)r * H_;
  for (int c = threadIdx.x; c < H_; c += 256) dst[c] = f2bf(src[c]);
}

// ---------------- f16 weight pack kernels (one-time) ----------------
// Wpe[k2*512+j] = uint4{ pack(Whh[g*512+j][2k2], [2k2+1]) : g=0..3 }, k2=0..255
__global__ __launch_bounds__(256) void k_pack_enc(const float* __restrict__ whh,
                                                  uint4* __restrict__ wpe) {
  int idx = blockIdx.x * 256 + threadIdx.x;  // 0..131071
  int k2 = idx >> 9, j = idx & 511;
  float2 r0 = *(const float2*)(whh + (size_t)(0 * 512 + j) * 512 + 2 * k2);
  float2 r1 = *(const float2*)(whh + (size_t)(1 * 512 + j + 512 - 512) * 512 + (size_t)512 * 512 + 2 * k2 - (size_t)512 * 512 + (size_t)(512) * 512 * 0);
  r1 = *(const float2*)(whh + (size_t)(512 + j) * 512 + 2 * k2);
  float2 r2 = *(const float2*)(whh + (size_t)(1024 + j) * 512 + 2 * k2);
  float2 r3 = *(const float2*)(whh + (size_t)(1536 + j) * 512 + 2 * k2);
  wpe[idx] = make_uint4(f2h2(r0.x, r0.y), f2h2(r1.x, r1.y), f2h2(r2.x, r2.y), f2h2(r3.x, r3.y));
}

// Wpd[k2*512+j]: k2<256 -> ctx cols of dWih (col 512+2k2); k2>=256 -> dWhh cols 2(k2-256)
__global__ __launch_bounds__(256) void k_pack_dec(const float* __restrict__ dwih,
                                                  const float* __restrict__ dwhh,
                                                  uint4* __restrict__ wpd) {
  int idx = blockIdx.x * 256 + threadIdx.x;  // 0..262143
  int k2 = idx >> 9, j = idx & 511;
  float2 r[4];
  if (k2 < 256) {
#pragma unroll
    for (int g = 0; g < 4; ++g)
      r[g] = *(const float2*)(dwih + (size_t)(g * 512 + j) * 1024 + 512 + 2 * k2);
  } else {
#pragma unroll
    for (int g = 0; g < 4; ++g)
      r[g] = *(const float2*)(dwhh + (size_t)(g * 512 + j) * 512 + 2 * (k2 - 256));
  }
  wpd[idx] = make_uint4(f2h2(r[0].x, r[0].y), f2h2(r[1].x, r[1].y),
                        f2h2(r[2].x, r[2].y), f2h2(r[3].x, r[3].y));
}

// WaT[k2*512+u] = pack(attnW[u][2k2], attnW[u][2k2+1])   (h-half: cols 0..511)
__global__ __launch_bounds__(256) void k_pack_attn(const float* __restrict__ attnw,
                                                   unsigned* __restrict__ wat) {
  int idx = blockIdx.x * 256 + threadIdx.x;  // 0..131071
  int k2 = idx >> 9, u = idx & 511;
  float2 r = *(const float2*)(attnw + (size_t)u * 1024 + 2 * k2);
  wat[idx] = f2h2(r.x, r.y);
}

// ---------------- bf16 MFMA GEMM: C[M,N] = A[M,K] * B[N,K]^T + bias ----------------
// OUT_MODE 0: row-major ldc=N
// OUT_MODE 1: row r=(l*64+b) -> out[(b*30+l)*N + col]   (FC)
// OUT_MODE 2: gate-packed: C[(row*512 + (col&511))*4 + (col>>9)]   (N must be 2048)
template <int OUT_MODE>
__global__ __launch_bounds__(256) void k_gemm(const unsigned short* __restrict__ A, int lda,
                                              const unsigned short* __restrict__ Bm, int ldb,
                                              float* __restrict__ C, int N, int K,
                                              const float* __restrict__ bias0,
                                              const float* __restrict__ bias1) {
  __shared__ __align__(16) unsigned short As[128 * 40];
  __shared__ __align__(16) unsigned short Bs[128 * 40];
  const int tid = threadIdx.x;
  const int m0 = blockIdx.y * 128, n0 = blockIdx.x * 128;
  const int wave = tid >> 6, lane = tid & 63;
  const int wm = wave >> 1, wn = wave & 1;
  const int lr = lane & 15, lk = lane >> 4;

  f32x4 acc[4][4];
#pragma unroll
  for (int m = 0; m < 4; ++m)
#pragma unroll
    for (int n = 0; n < 4; ++n) acc[m][n] = (f32x4){0.f, 0.f, 0.f, 0.f};

  const int c0 = tid, c1 = tid + 256;
  const int ar0 = c0 >> 2, as0 = c0 & 3;
  const int ar1 = c1 >> 2, as1 = c1 & 3;

  for (int k0 = 0; k0 < K; k0 += 32) {
    uint4 va0 = *(const uint4*)(A + (size_t)(m0 + ar0) * lda + k0 + as0 * 8);
    uint4 va1 = *(const uint4*)(A + (size_t)(m0 + ar1) * lda + k0 + as1 * 8);
    uint4 vb0 = *(const uint4*)(Bm + (size_t)(n0 + ar0) * ldb + k0 + as0 * 8);
    uint4 vb1 = *(const uint4*)(Bm + (size_t)(n0 + ar1) * ldb + k0 + as1 * 8);
    *(uint4*)(As + ar0 * 40 + as0 * 8) = va0;
    *(uint4*)(As + ar1 * 40 + as1 * 8) = va1;
    *(uint4*)(Bs + ar0 * 40 + as0 * 8) = vb0;
    *(uint4*)(Bs + ar1 * 40 + as1 * 8) = vb1;
    __syncthreads();
    bf16x8 af[4], bfr[4];
#pragma unroll
    for (int m = 0; m < 4; ++m)
      af[m] = *(const bf16x8*)(As + (wm * 64 + m * 16 + lr) * 40 + lk * 8);
#pragma unroll
    for (int n = 0; n < 4; ++n)
      bfr[n] = *(const bf16x8*)(Bs + (wn * 64 + n * 16 + lr) * 40 + lk * 8);
#pragma unroll
    for (int m = 0; m < 4; ++m)
#pragma unroll
      for (int n = 0; n < 4; ++n)
        acc[m][n] = __builtin_amdgcn_mfma_f32_16x16x32_bf16(af[m], bfr[n], acc[m][n], 0, 0, 0);
    __syncthreads();
  }
#pragma unroll
  for (int m = 0; m < 4; ++m) {
#pragma unroll
    for (int n = 0; n < 4; ++n) {
      const int col = n0 + wn * 64 + n * 16 + lr;
      float bv = (bias0 ? bias0[col] : 0.f) + (bias1 ? bias1[col] : 0.f);
#pragma unroll
      for (int j = 0; j < 4; ++j) {
        const int row = m0 + wm * 64 + m * 16 + lk * 4 + j;
        float v = acc[m][n][j] + bv;
        if (OUT_MODE == 0) {
          C[(size_t)row * N + col] = v;
        } else if (OUT_MODE == 1) {
          int l = row >> 6, b = row & 63;
          C[((size_t)b * NDEC + l) * (size_t)N + col] = v;
        } else {
          C[((size_t)row * 512 + (col & 511)) * 4 + (col >> 9)] = v;
        }
      }
    }
  }
}

// ---------------- encoder: block b, thread j owns unit j; no grid sync ----------------
__global__ __launch_bounds__(512) void k_enc2(const float4* __restrict__ xg4,  // [(b*80+t)*512+j] gates i,f,g,o
                                              const uint4* __restrict__ wpe,   // [k2*512+j]
                                              float* __restrict__ encf,
                                              unsigned short* __restrict__ encbf,
                                              float* __restrict__ cfin) {
  __shared__ __align__(16) unsigned short h16[512];
  const int b = blockIdx.x, j = threadIdx.x;
  h16[j] = 0;
  float c = 0.f;
  __syncthreads();
  for (int t = 0; t < T_; ++t) {
    float4 a = xg4[((size_t)b * T_ + t) * 512 + j];
    const uint4* hp4 = (const uint4*)h16;
#pragma unroll 4
    for (int k8 = 0; k8 < 64; ++k8) {
      uint4 hv = hp4[k8];
      uint4 w0 = wpe[((k8 * 4 + 0) << 9) | j];
      uint4 w1 = wpe[((k8 * 4 + 1) << 9) | j];
      uint4 w2 = wpe[((k8 * 4 + 2) << 9) | j];
      uint4 w3 = wpe[((k8 * 4 + 3) << 9) | j];
      a.x = fdot2(hv.x, w0.x, a.x); a.y = fdot2(hv.x, w0.y, a.y);
      a.z = fdot2(hv.x, w0.z, a.z); a.w = fdot2(hv.x, w0.w, a.w);
      a.x = fdot2(hv.y, w1.x, a.x); a.y = fdot2(hv.y, w1.y, a.y);
      a.z = fdot2(hv.y, w1.z, a.z); a.w = fdot2(hv.y, w1.w, a.w);
      a.x = fdot2(hv.z, w2.x, a.x); a.y = fdot2(hv.z, w2.y, a.y);
      a.z = fdot2(hv.z, w2.z, a.z); a.w = fdot2(hv.z, w2.w, a.w);
      a.x = fdot2(hv.w, w3.x, a.x); a.y = fdot2(hv.w, w3.y, a.y);
      a.z = fdot2(hv.w, w3.z, a.z); a.w = fdot2(hv.w, w3.w, a.w);
    }
    c = sigmoidf(a.y) * c + sigmoidf(a.x) * tanh_fast(a.z);
    float h = sigmoidf(a.w) * tanh_fast(c);
    __syncthreads();           // all reads of h16 for this step done
    h16[j] = f2h(h);
    size_t o = ((size_t)b * T_ + t) * 512 + j;
    encf[o] = h;
    encbf[o] = f2bf(h);
    __syncthreads();           // new h visible
  }
  cfin[b * 512 + j] = c;
}

// ---------------- decoder: block b, thread j owns unit j; no grid sync ----------------
__global__ __launch_bounds__(512) void k_dec2(const uint4* __restrict__ wpd,   // [k2*512+j], k=[ctx;h]
                                              const unsigned* __restrict__ wat,// [k2*512+u]
                                              const float* __restrict__ vw,
                                              const float4* __restrict__ eg4,  // [(l*64+b)*512+j]
                                              const float* __restrict__ encpart,
                                              const float* __restrict__ encf,
                                              const float* __restrict__ cfin,
                                              unsigned short* __restrict__ hsbf) {
  __shared__ __align__(16) unsigned short xv16[1024];  // [ctx f16 (512); h f16 (512)]
  __shared__ float hw[512];
  __shared__ float vsm[512];
  __shared__ float sc[80], wts[80];
  const int b = blockIdx.x, j = threadIdx.x;
  vsm[j] = vw[j];
  xv16[512 + j] = f2h(encf[((size_t)b * T_ + (T_ - 1)) * 512 + j]);
  float c = cfin[b * 512 + j];
  __syncthreads();

  for (int l = 0; l < NDEC; ++l) {
    // 1. hW[u] = h . Wa_h[u,:]
    {
      const uint4* xh4 = (const uint4*)(xv16 + 512);
      float s = 0.f;
#pragma unroll 4
      for (int k8 = 0; k8 < 64; ++k8) {
        uint4 hv = xh4[k8];
        s = fdot2(hv.x, wat[((k8 * 4 + 0) << 9) | j], s);
        s = fdot2(hv.y, wat[((k8 * 4 + 1) << 9) | j], s);
        s = fdot2(hv.z, wat[((k8 * 4 + 2) << 9) | j], s);
        s = fdot2(hv.w, wat[((k8 * 4 + 3) << 9) | j], s);
      }
      hw[j] = s;
    }
    __syncthreads();
    // 2. scores: wave wv handles t = wv, wv+8, ...
    {
      const int wv = j >> 6, ln = j & 63;
      for (int t = wv; t < T_; t += 8) {
        const float* ep = encpart + ((size_t)b * T_ + t) * 512;
        float p = 0.f;
#pragma unroll
        for (int m = 0; m < 8; ++m) {
          int u = ln + m * 64;
          p += vsm[u] * tanh_fast(hw[u] + ep[u]);
        }
#pragma unroll
        for (int m = 1; m < 64; m <<= 1) p += __shfl_xor(p, m, 64);
        if (ln == 0) sc[t] = p;
      }
    }
    __syncthreads();
    // 3. softmax over 80 (wave 0)
    if (j < 64) {
      float x0 = sc[j];
      float x1 = (j < T_ - 64) ? sc[64 + j] : -1e30f;
      float mx = fmaxf(x0, x1);
#pragma unroll
      for (int m = 1; m < 64; m <<= 1) mx = fmaxf(mx, __shfl_xor(mx, m, 64));
      float e0 = __expf(x0 - mx);
      float e1 = (j < T_ - 64) ? __expf(x1 - mx) : 0.f;
      float sm = e0 + e1;
#pragma unroll
      for (int m = 1; m < 64; m <<= 1) sm += __shfl_xor(sm, m, 64);
      wts[j] = e0 / sm;
      if (j < T_ - 64) wts[64 + j] = e1 / sm;
    }
    __syncthreads();
    // 4. ctx[j] = sum_t wts[t] * encf[b][t][j]
    {
      const float* eb = encf + (size_t)b * T_ * 512 + j;
      float a0 = 0.f;
#pragma unroll 8
      for (int t = 0; t < T_; ++t) a0 += wts[t] * eb[(size_t)t * 512];
      xv16[j] = f2h(a0);
    }
    __syncthreads();
    // 5. gates over [ctx; h]
    float4 a = eg4[((size_t)l * 64 + b) * 512 + j];
    {
      const uint4* xp4 = (const uint4*)xv16;
#pragma unroll 4
      for (int k8 = 0; k8 < 128; ++k8) {
        uint4 hv = xp4[k8];
        uint4 w0 = wpd[((k8 * 4 + 0) << 9) | j];
        uint4 w1 = wpd[((k8 * 4 + 1) << 9) | j];
        uint4 w2 = wpd[((k8 * 4 + 2) << 9) | j];
        uint4 w3 = wpd[((k8 * 4 + 3) << 9) | j];
        a.x = fdot2(hv.x, w0.x, a.x); a.y = fdot2(hv.x, w0.y, a.y);
        a.z = fdot2(hv.x, w0.z, a.z); a.w = fdot2(hv.x, w0.w, a.w);
        a.x = fdot2(hv.y, w1.x, a.x); a.y = fdot2(hv.y, w1.y, a.y);
        a.z = fdot2(hv.y, w1.z, a.z); a.w = fdot2(hv.y, w1.w, a.w);
        a.x = fdot2(hv.z, w2.x, a.x); a.y = fdot2(hv.z, w2.y, a.y);
        a.z = fdot2(hv.z, w2.z, a.z); a.w = fdot2(hv.z, w2.w, a.w);
        a.x = fdot2(hv.w, w3.x, a.x); a.y = fdot2(hv.w, w3.y, a.y);
        a.z = fdot2(hv.w, w3.z, a.z); a.w = fdot2(hv.w, w3.w, a.w);
      }
    }
    c = sigmoidf(a.y) * c + sigmoidf(a.x) * tanh_fast(a.z);
    float h = sigmoidf(a.w) * tanh_fast(c);
    __syncthreads();           // gates loop reads of xv16 h-part done
    xv16[512 + j] = f2h(h);
    hsbf[((size_t)l * 64 + b) * 512 + j] = f2bf(h);
    __syncthreads();
  }
}

// ---------------- launch ----------------
extern "C" void kernel_launch(void* const* d_in, const int* in_sizes, int n_in,
                              void* d_out, int out_size, void* d_ws, size_t ws_size,
                              hipStream_t stream) {
  const float* video = (const float*)d_in[0];
  const int* captions = (const int*)d_in[1];
  const float* emb = (const float*)d_in[2];
  const float* eWih = (const float*)d_in[3];
  const float* eWhh = (const float*)d_in[4];
  const float* ebih = (const float*)d_in[5];
  const float* ebhh = (const float*)d_in[6];
  const float* attnW = (const float*)d_in[7];
  const float* attnb = (const float*)d_in[8];
  const float* vw = (const float*)d_in[9];
  const float* dWih = (const float*)d_in[10];
  const float* dWhh = (const float*)d_in[11];
  const float* dbih = (const float*)d_in[12];
  const float* dbhh = (const float*)d_in[13];
  const float* fcW = (const float*)d_in[14];
  const float* fcb = (const float*)d_in[15];

  char* ws = (char*)d_ws;
  unsigned short* vid_bf = (unsigned short*)(ws + 0);            // 41,943,040 B (dead after K1)
  unsigned short* fcw_bf = (unsigned short*)(ws + 0);            // 32,768,000 B (after K1)
  unsigned short* hs_bf = (unsigned short*)(ws + 33554432ull);   // 1,966,080 B -> ends 35,520,512
  uint4* wpd = (uint4*)(ws + 35520512ull);                       // 4,194,304 B -> 39,714,816 (after K1)
  uint4* wpe = (uint4*)(ws + 39714816ull);                       // 2,097,152 B -> 41,811,968 (after K1)
  float* xg4 = (float*)(ws + 41943040ull);                       // 41,943,040 B (dead after enc)
  float* encpart = (float*)(ws + 41943040ull);                   // 10,485,760 B (after enc)
  float* eg4 = (float*)(ws + 52428800ull);                       // 15,728,640 B (after enc)
  unsigned short* aemb = (unsigned short*)(ws + 68157440ull);    // 1,966,080 B (after enc)
  unsigned short* ewih_bf = (unsigned short*)(ws + 83886080ull); // 16,777,216 B
  float* encf = (float*)(ws + 100663296ull);                     // 10,485,760 B
  unsigned short* encbf = (unsigned short*)(ws + 111149056ull);  // 5,242,880 B
  unsigned short* attnw_bf = (unsigned short*)(ws + 116391936ull); // 1,048,576 B
  unsigned short* dwih_bf = (unsigned short*)(ws + 117440512ull);  // 4,194,304 B
  unsigned* wat = (unsigned*)(ws + 121634816ull);                // 524,288 B -> 122,159,104
  float* cfin = (float*)(ws + 122159104ull);                     // 131,072 B -> 122,290,176
  int* flag = (int*)(ws + 122290176ull);

  auto cvt = [&](const float* in, unsigned short* out, long n) {
    long n4 = n / 4;
    int blocks = (int)((n4 + 255) / 256);
    if (blocks > 2048) blocks = 2048;
    k_cvt<<<blocks, 256, 0, stream>>>(in, out, n4);
  };
  cvt(video, vid_bf, 5120L * 4096);
  cvt(eWih, ewih_bf, 2048L * 4096);
  cvt(attnW, attnw_bf, 512L * 1024);
  cvt(dWih, dwih_bf, 2048L * 1024);
  k_detect_i64<<<1, 256, 0, stream>>>(captions, flag);

  // K1: X_gates = video @ enc_Wih^T + ebih + ebhh  -> gate-packed [r][j][4]
  k_gemm<2><<<dim3(16, 40), 256, 0, stream>>>(vid_bf, 4096, ewih_bf, 4096, xg4, 2048, 4096, ebih, ebhh);
  cvt(fcW, fcw_bf, 32000L * 512);

  // f16 weight packs (write into vid_bf's old region -> must follow K1)
  k_pack_enc<<<512, 256, 0, stream>>>(eWhh, wpe);
  k_pack_dec<<<1024, 256, 0, stream>>>(dWih, dWhh, wpd);
  k_pack_attn<<<512, 256, 0, stream>>>(attnW, wat);

  k_enc2<<<64, 512, 0, stream>>>((const float4*)xg4, wpe, encf, encbf, cfin);

  k_gather_emb<<<1920, 256, 0, stream>>>(emb, captions, flag, aemb);
  // EncPart = enc_out @ attn_W[:,512:]^T + attn_b   [5120 x 512]
  k_gemm<0><<<dim3(4, 40), 256, 0, stream>>>(encbf, 512, attnw_bf + 512, 1024, encpart, 512, 512, attnb, nullptr);
  // E_gates = emb[tok] @ dec_Wih[:,:512]^T + dbih + dbhh -> gate-packed [r][j][4]
  k_gemm<2><<<dim3(16, 15), 256, 0, stream>>>(aemb, 512, dwih_bf, 1024, eg4, 2048, 512, dbih, dbhh);

  k_dec2<<<64, 512, 0, stream>>>(wpd, wat, vw, (const float4*)eg4, encpart, encf, cfin, hs_bf);

  // FC: out[b][l][v] = Hs @ fc_W^T + fc_b   [1920 x 32000]
  k_gemm<1><<<dim3(250, 15), 256, 0, stream>>>(hs_bf, 512, fcw_bf, 512, (float*)d_out, 32000, 512, fcb, nullptr);
}

// Round 6
// 3168.120 us; speedup vs baseline: 3.6204x; 1.0184x over previous
//
#include <hip/hip_runtime.h>

// S2VT + attention — R6: barrier-free batch-parallel recurrence + deep MLP.
//  R5 was latency-bound (6% occupancy, ~500 GB/s in-flight limit). R6:
//  1024 threads/block (16 waves/CU), k-split halves with LDS combine,
//  2-accumulator unrolled inner loops (16 outstanding uint4 loads), uint4
//  attn-weight pack, float4 ctx phase. Weights f16 + v_dot2_f32_f16.

#define DEV __device__ __forceinline__

typedef __attribute__((ext_vector_type(4))) float f32x4;
typedef __attribute__((ext_vector_type(8))) short bf16x8;
typedef _Float16 half2_t __attribute__((ext_vector_type(2)));

static constexpr int B_ = 64, T_ = 80, H_ = 512, L_ = 31, NDEC = 30;

DEV unsigned short f2bf(float f) {
  unsigned u = __builtin_bit_cast(unsigned, f);
  u += 0x7FFF + ((u >> 16) & 1);
  return (unsigned short)(u >> 16);
}
DEV unsigned short f2h(float x) {
  return __builtin_bit_cast(unsigned short, (_Float16)x);
}
DEV unsigned f2h2(float lo, float hi) {
  return (unsigned)f2h(lo) | ((unsigned)f2h(hi) << 16);
}
DEV float fdot2(unsigned x, unsigned w, float acc) {
  return __builtin_amdgcn_fdot2(__builtin_bit_cast(half2_t, x),
                                __builtin_bit_cast(half2_t, w), acc, false);
}
// accumulate 8 k's (one uint4 of f16 x) against 4 gate-weight uint4s
DEV float4 acc8(float4 a, uint4 hv, uint4 w0, uint4 w1, uint4 w2, uint4 w3) {
  a.x = fdot2(hv.x, w0.x, a.x); a.y = fdot2(hv.x, w0.y, a.y);
  a.z = fdot2(hv.x, w0.z, a.z); a.w = fdot2(hv.x, w0.w, a.w);
  a.x = fdot2(hv.y, w1.x, a.x); a.y = fdot2(hv.y, w1.y, a.y);
  a.z = fdot2(hv.y, w1.z, a.z); a.w = fdot2(hv.y, w1.w, a.w);
  a.x = fdot2(hv.z, w2.x, a.x); a.y = fdot2(hv.z, w2.y, a.y);
  a.z = fdot2(hv.z, w2.z, a.z); a.w = fdot2(hv.z, w2.w, a.w);
  a.x = fdot2(hv.w, w3.x, a.x); a.y = fdot2(hv.w, w3.y, a.y);
  a.z = fdot2(hv.w, w3.z, a.z); a.w = fdot2(hv.w, w3.w, a.w);
  return a;
}
DEV float accS(float s, uint4 hv, uint4 w) {
  s = fdot2(hv.x, w.x, s); s = fdot2(hv.y, w.y, s);
  s = fdot2(hv.z, w.z, s); s = fdot2(hv.w, w.w, s);
  return s;
}
DEV float sigmoidf(float x) { return 1.f / (1.f + __expf(-x)); }
DEV float tanh_fast(float x) { float e = __expf(2.f * x); return (e - 1.f) / (e + 1.f); }

// ---------------- fp32 -> bf16 convert ----------------
__global__ __launch_bounds__(256) void k_cvt(const float* __restrict__ in,
                                             unsigned short* __restrict__ out, long n4) {
  long i = (long)blockIdx.x * 256 + threadIdx.x;
  long stride = (long)gridDim.x * 256;
  for (; i < n4; i += stride) {
    float4 v = reinterpret_cast<const float4*>(in)[i];
    ushort4 o;
    o.x = f2bf(v.x); o.y = f2bf(v.y); o.z = f2bf(v.z); o.w = f2bf(v.w);
    reinterpret_cast<ushort4*>(out)[i] = o;
  }
}

// ---------------- int64-vs-int32 caption detect ----------------
__global__ void k_detect_i64(const int* __restrict__ cap, int* __restrict__ flag) {
  __shared__ int s;
  if (threadIdx.x == 0) s = 0;
  __syncthreads();
  int acc = 0;
  for (int i = threadIdx.x; i < (B_ * L_) / 2; i += 256) acc |= cap[2 * i + 1];
  if (acc) atomicOr(&s, 1);
  __syncthreads();
  if (threadIdx.x == 0) flag[0] = (s == 0) ? 1 : 0;
}

// ---------------- embedding gather (rows r = l*64+b) ----------------
__global__ __launch_bounds__(256) void k_gather_emb(const float* __restrict__ emb,
                                                    const int* __restrict__ cap,
                                                    const int* __restrict__ flag,
                                                    unsigned short* __restrict__ aemb) {
  int r = blockIdx.x;
  int l = r >> 6, b = r & 63;
  int ci = b * L_ + l;
  int tok = flag[0] ? cap[2 * ci] : cap[ci];
  const float* src = emb + (size_t)tok * H_;
  unsigned short* dst = aemb + (size_t)r * H_;
  for (int c = threadIdx.x; c < H_; c += 256) dst[c] = f2bf(src[c]);
}

// ---------------- f16 weight pack kernels (one-time) ----------------
__global__ __launch_bounds__(256) void k_pack_enc(const float* __restrict__ whh,
                                                  uint4* __restrict__ wpe) {
  int idx = blockIdx.x * 256 + threadIdx.x;  // k2(256) x j(512)
  int k2 = idx >> 9, j = idx & 511;
  float2 r0 = *(const float2*)(whh + (size_t)(j) * 512 + 2 * k2);
  float2 r1 = *(const float2*)(whh + (size_t)(512 + j) * 512 + 2 * k2);
  float2 r2 = *(const float2*)(whh + (size_t)(1024 + j) * 512 + 2 * k2);
  float2 r3 = *(const float2*)(whh + (size_t)(1536 + j) * 512 + 2 * k2);
  wpe[idx] = make_uint4(f2h2(r0.x, r0.y), f2h2(r1.x, r1.y), f2h2(r2.x, r2.y), f2h2(r3.x, r3.y));
}

__global__ __launch_bounds__(256) void k_pack_dec(const float* __restrict__ dwih,
                                                  const float* __restrict__ dwhh,
                                                  uint4* __restrict__ wpd) {
  int idx = blockIdx.x * 256 + threadIdx.x;  // k2(512) x j(512)
  int k2 = idx >> 9, j = idx & 511;
  float2 r[4];
  if (k2 < 256) {
#pragma unroll
    for (int g = 0; g < 4; ++g)
      r[g] = *(const float2*)(dwih + (size_t)(g * 512 + j) * 1024 + 512 + 2 * k2);
  } else {
#pragma unroll
    for (int g = 0; g < 4; ++g)
      r[g] = *(const float2*)(dwhh + (size_t)(g * 512 + j) * 512 + 2 * (k2 - 256));
  }
  wpd[idx] = make_uint4(f2h2(r[0].x, r[0].y), f2h2(r[1].x, r[1].y),
                        f2h2(r[2].x, r[2].y), f2h2(r[3].x, r[3].y));
}

// wat2[k8*512+u] = 4 packed pairs covering h dims 8k8..8k8+7 of attnW row u
__global__ __launch_bounds__(256) void k_pack_attn2(const float* __restrict__ attnw,
                                                    uint4* __restrict__ wat2) {
  int idx = blockIdx.x * 256 + threadIdx.x;  // k8(64) x u(512) = 32768
  int k8 = idx >> 9, u = idx & 511;
  const float* p = attnw + (size_t)u * 1024 + 8 * k8;
  wat2[idx] = make_uint4(f2h2(p[0], p[1]), f2h2(p[2], p[3]),
                         f2h2(p[4], p[5]), f2h2(p[6], p[7]));
}

// ---------------- bf16 MFMA GEMM: C[M,N] = A[M,K] * B[N,K]^T + bias ----------------
// OUT_MODE 0: row-major; 1: FC row remap; 2: gate-packed [row][j][4]
template <int OUT_MODE>
__global__ __launch_bounds__(256) void k_gemm(const unsigned short* __restrict__ A, int lda,
                                              const unsigned short* __restrict__ Bm, int ldb,
                                              float* __restrict__ C, int N, int K,
                                              const float* __restrict__ bias0,
                                              const float* __restrict__ bias1) {
  __shared__ __align__(16) unsigned short As[128 * 40];
  __shared__ __align__(16) unsigned short Bs[128 * 40];
  const int tid = threadIdx.x;
  const int m0 = blockIdx.y * 128, n0 = blockIdx.x * 128;
  const int wave = tid >> 6, lane = tid & 63;
  const int wm = wave >> 1, wn = wave & 1;
  const int lr = lane & 15, lk = lane >> 4;

  f32x4 acc[4][4];
#pragma unroll
  for (int m = 0; m < 4; ++m)
#pragma unroll
    for (int n = 0; n < 4; ++n) acc[m][n] = (f32x4){0.f, 0.f, 0.f, 0.f};

  const int c0 = tid, c1 = tid + 256;
  const int ar0 = c0 >> 2, as0 = c0 & 3;
  const int ar1 = c1 >> 2, as1 = c1 & 3;

  for (int k0 = 0; k0 < K; k0 += 32) {
    uint4 va0 = *(const uint4*)(A + (size_t)(m0 + ar0) * lda + k0 + as0 * 8);
    uint4 va1 = *(const uint4*)(A + (size_t)(m0 + ar1) * lda + k0 + as1 * 8);
    uint4 vb0 = *(const uint4*)(Bm + (size_t)(n0 + ar0) * ldb + k0 + as0 * 8);
    uint4 vb1 = *(const uint4*)(Bm + (size_t)(n0 + ar1) * ldb + k0 + as1 * 8);
    *(uint4*)(As + ar0 * 40 + as0 * 8) = va0;
    *(uint4*)(As + ar1 * 40 + as1 * 8) = va1;
    *(uint4*)(Bs + ar0 * 40 + as0 * 8) = vb0;
    *(uint4*)(Bs + ar1 * 40 + as1 * 8) = vb1;
    __syncthreads();
    bf16x8 af[4], bfr[4];
#pragma unroll
    for (int m = 0; m < 4; ++m)
      af[m] = *(const bf16x8*)(As + (wm * 64 + m * 16 + lr) * 40 + lk * 8);
#pragma unroll
    for (int n = 0; n < 4; ++n)
      bfr[n] = *(const bf16x8*)(Bs + (wn * 64 + n * 16 + lr) * 40 + lk * 8);
#pragma unroll
    for (int m = 0; m < 4; ++m)
#pragma unroll
      for (int n = 0; n < 4; ++n)
        acc[m][n] = __builtin_amdgcn_mfma_f32_16x16x32_bf16(af[m], bfr[n], acc[m][n], 0, 0, 0);
    __syncthreads();
  }
#pragma unroll
  for (int m = 0; m < 4; ++m) {
#pragma unroll
    for (int n = 0; n < 4; ++n) {
      const int col = n0 + wn * 64 + n * 16 + lr;
      float bv = (bias0 ? bias0[col] : 0.f) + (bias1 ? bias1[col] : 0.f);
#pragma unroll
      for (int j = 0; j < 4; ++j) {
        const int row = m0 + wm * 64 + m * 16 + lk * 4 + j;
        float v = acc[m][n][j] + bv;
        if (OUT_MODE == 0) {
          C[(size_t)row * N + col] = v;
        } else if (OUT_MODE == 1) {
          int l = row >> 6, b = row & 63;
          C[((size_t)b * NDEC + l) * (size_t)N + col] = v;
        } else {
          C[((size_t)row * 512 + (col & 511)) * 4 + (col >> 9)] = v;
        }
      }
    }
  }
}

// ---------------- encoder: block b, 1024 thr, (j, half) k-split ----------------
__global__ __launch_bounds__(1024) void k_enc3(const float4* __restrict__ xg4,
                                               const uint4* __restrict__ wpe,
                                               float* __restrict__ encf,
                                               unsigned short* __restrict__ encbf,
                                               float* __restrict__ cfin) {
  __shared__ __align__(16) unsigned short h16[512];
  __shared__ __align__(16) float4 psum[512];
  const int b = blockIdx.x, tid = threadIdx.x;
  const int j = tid & 511, half = tid >> 9;
  if (tid < 512) h16[j] = 0;
  float c = 0.f;
  __syncthreads();
  const uint4* hp4 = (const uint4*)h16;
  const int base = half * 32;
  for (int t = 0; t < T_; ++t) {
    float4 xa = {0.f, 0.f, 0.f, 0.f};
    if (half == 0) xa = xg4[((size_t)b * T_ + t) * 512 + j];
    float4 a0 = {0.f, 0.f, 0.f, 0.f}, a1 = a0;
#pragma unroll 2
    for (int k8 = base; k8 < base + 32; k8 += 2) {
      uint4 h0 = hp4[k8], h1 = hp4[k8 + 1];
      uint4 w00 = wpe[((k8 * 4 + 0) << 9) | j];
      uint4 w01 = wpe[((k8 * 4 + 1) << 9) | j];
      uint4 w02 = wpe[((k8 * 4 + 2) << 9) | j];
      uint4 w03 = wpe[((k8 * 4 + 3) << 9) | j];
      uint4 w10 = wpe[((k8 * 4 + 4) << 9) | j];
      uint4 w11 = wpe[((k8 * 4 + 5) << 9) | j];
      uint4 w12 = wpe[((k8 * 4 + 6) << 9) | j];
      uint4 w13 = wpe[((k8 * 4 + 7) << 9) | j];
      a0 = acc8(a0, h0, w00, w01, w02, w03);
      a1 = acc8(a1, h1, w10, w11, w12, w13);
    }
    if (half) psum[j] = make_float4(a0.x + a1.x, a0.y + a1.y, a0.z + a1.z, a0.w + a1.w);
    __syncthreads();
    if (half == 0) {
      float4 p = psum[j];
      float gi = xa.x + a0.x + a1.x + p.x;
      float gf = xa.y + a0.y + a1.y + p.y;
      float gg = xa.z + a0.z + a1.z + p.z;
      float go = xa.w + a0.w + a1.w + p.w;
      c = sigmoidf(gf) * c + sigmoidf(gi) * tanh_fast(gg);
      float h = sigmoidf(go) * tanh_fast(c);
      h16[j] = f2h(h);
      size_t o = ((size_t)b * T_ + t) * 512 + j;
      encf[o] = h;
      encbf[o] = f2bf(h);
      if (t == T_ - 1) cfin[b * 512 + j] = c;
    }
    __syncthreads();
  }
}

// ---------------- decoder: block b, 1024 thr, (j, half) k-split ----------------
__global__ __launch_bounds__(1024) void k_dec3(const uint4* __restrict__ wpd,
                                               const uint4* __restrict__ wat2,
                                               const float* __restrict__ vw,
                                               const float4* __restrict__ eg4,
                                               const float* __restrict__ encpart,
                                               const float* __restrict__ encf,
                                               const float* __restrict__ cfin,
                                               unsigned short* __restrict__ hsbf) {
  __shared__ __align__(16) unsigned short xv16[1024];  // [ctx f16; h f16]
  __shared__ float hw[512];
  __shared__ float vsm[512];
  __shared__ float sc[80], wts[80];
  __shared__ __align__(16) float4 psum[512];
  __shared__ __align__(16) float4 ctxp[1024];  // [8][128]
  const int b = blockIdx.x, tid = threadIdx.x;
  const int j = tid & 511, half = tid >> 9;
  float c = 0.f;
  if (tid < 512) {
    vsm[j] = vw[j];
    xv16[512 + j] = f2h(encf[((size_t)b * T_ + (T_ - 1)) * 512 + j]);
    c = cfin[b * 512 + j];
  }
  __syncthreads();
  const uint4* xp4 = (const uint4*)xv16;
  const uint4* xh4 = (const uint4*)(xv16) + 64;
  float* psumF = (float*)psum;
  const float* cp = (const float*)ctxp;

  for (int l = 0; l < NDEC; ++l) {
    // 1. hW partials (h . Wa_h), k8 in [half*32, half*32+32)
    {
      float s0 = 0.f, s1 = 0.f;
#pragma unroll 2
      for (int k8 = half * 32; k8 < half * 32 + 32; k8 += 2) {
        uint4 h0 = xh4[k8], h1 = xh4[k8 + 1];
        uint4 w0 = wat2[(k8 << 9) | j], w1 = wat2[((k8 + 1) << 9) | j];
        s0 = accS(s0, h0, w0);
        s1 = accS(s1, h1, w1);
      }
      if (half) psumF[j] = s0 + s1;
      __syncthreads();
      if (half == 0) hw[j] = s0 + s1 + psumF[j];
    }
    __syncthreads();
    // 2. scores: 16 waves, t strided
    {
      const int wv = tid >> 6, ln = tid & 63;
      for (int t = wv; t < T_; t += 16) {
        const float* ep = encpart + ((size_t)b * T_ + t) * 512;
        float p = 0.f;
#pragma unroll
        for (int m = 0; m < 8; ++m) {
          int u = ln + m * 64;
          p += vsm[u] * tanh_fast(hw[u] + ep[u]);
        }
#pragma unroll
        for (int m = 1; m < 64; m <<= 1) p += __shfl_xor(p, m, 64);
        if (ln == 0) sc[t] = p;
      }
    }
    __syncthreads();
    // 3. softmax over 80 (wave 0)
    if (tid < 64) {
      float x0 = sc[tid];
      float x1 = (tid < T_ - 64) ? sc[64 + tid] : -1e30f;
      float mx = fmaxf(x0, x1);
#pragma unroll
      for (int m = 1; m < 64; m <<= 1) mx = fmaxf(mx, __shfl_xor(mx, m, 64));
      float e0 = __expf(x0 - mx);
      float e1 = (tid < T_ - 64) ? __expf(x1 - mx) : 0.f;
      float sm = e0 + e1;
#pragma unroll
      for (int m = 1; m < 64; m <<= 1) sm += __shfl_xor(sm, m, 64);
      wts[tid] = e0 / sm;
      if (tid < T_ - 64) wts[64 + tid] = e1 / sm;
    }
    __syncthreads();
    // 4. ctx partials: tq=tid>>7 handles t = tq, tq+8, ...
    {
      const int tq = tid >> 7, j4 = tid & 127;
      const float4* eb = (const float4*)(encf + (size_t)b * T_ * 512) + j4;
      float4 acc = {0.f, 0.f, 0.f, 0.f};
      for (int t = tq; t < T_; t += 8) {
        float w = wts[t];
        float4 e = eb[(size_t)t * 128];
        acc.x += w * e.x; acc.y += w * e.y; acc.z += w * e.z; acc.w += w * e.w;
      }
      ctxp[tq * 128 + j4] = acc;
    }
    __syncthreads();
    // 5. ctx combine -> xv16[0..511]
    if (tid < 512) {
      float v = cp[j] + cp[512 + j] + cp[1024 + j] + cp[1536 + j] +
                cp[2048 + j] + cp[2560 + j] + cp[3072 + j] + cp[3584 + j];
      xv16[j] = f2h(v);
    }
    __syncthreads();
    // 6. gates partials over [ctx; h], k8 in [half*64, half*64+64)
    float4 xa = {0.f, 0.f, 0.f, 0.f};
    if (half == 0) xa = eg4[((size_t)l * 64 + b) * 512 + j];
    {
      float4 a0 = {0.f, 0.f, 0.f, 0.f}, a1 = a0;
#pragma unroll 2
      for (int k8 = half * 64; k8 < half * 64 + 64; k8 += 2) {
        uint4 h0 = xp4[k8], h1 = xp4[k8 + 1];
        uint4 w00 = wpd[((k8 * 4 + 0) << 9) | j];
        uint4 w01 = wpd[((k8 * 4 + 1) << 9) | j];
        uint4 w02 = wpd[((k8 * 4 + 2) << 9) | j];
        uint4 w03 = wpd[((k8 * 4 + 3) << 9) | j];
        uint4 w10 = wpd[((k8 * 4 + 4) << 9) | j];
        uint4 w11 = wpd[((k8 * 4 + 5) << 9) | j];
        uint4 w12 = wpd[((k8 * 4 + 6) << 9) | j];
        uint4 w13 = wpd[((k8 * 4 + 7) << 9) | j];
        a0 = acc8(a0, h0, w00, w01, w02, w03);
        a1 = acc8(a1, h1, w10, w11, w12, w13);
      }
      if (half) psum[j] = make_float4(a0.x + a1.x, a0.y + a1.y, a0.z + a1.z, a0.w + a1.w);
      __syncthreads();
      if (half == 0) {
        float4 p = psum[j];
        float gi = xa.x + a0.x + a1.x + p.x;
        float gf = xa.y + a0.y + a1.y + p.y;
        float gg = xa.z + a0.z + a1.z + p.z;
        float go = xa.w + a0.w + a1.w + p.w;
        c = sigmoidf(gf) * c + sigmoidf(gi) * tanh_fast(gg);
        float h = sigmoidf(go) * tanh_fast(c);
        xv16[512 + j] = f2h(h);
        hsbf[((size_t)l * 64 + b) * 512 + j] = f2bf(h);
      }
    }
    __syncthreads();
  }
}

// ---------------- launch ----------------
extern "C" void kernel_launch(void* const* d_in, const int* in_sizes, int n_in,
                              void* d_out, int out_size, void* d_ws, size_t ws_size,
                              hipStream_t stream) {
  const float* video = (const float*)d_in[0];
  const int* captions = (const int*)d_in[1];
  const float* emb = (const float*)d_in[2];
  const float* eWih = (const float*)d_in[3];
  const float* eWhh = (const float*)d_in[4];
  const float* ebih = (const float*)d_in[5];
  const float* ebhh = (const float*)d_in[6];
  const float* attnW = (const float*)d_in[7];
  const float* attnb = (const float*)d_in[8];
  const float* vw = (const float*)d_in[9];
  const float* dWih = (const float*)d_in[10];
  const float* dWhh = (const float*)d_in[11];
  const float* dbih = (const float*)d_in[12];
  const float* dbhh = (const float*)d_in[13];
  const float* fcW = (const float*)d_in[14];
  const float* fcb = (const float*)d_in[15];

  char* ws = (char*)d_ws;
  unsigned short* vid_bf = (unsigned short*)(ws + 0);            // dead after K1
  unsigned short* fcw_bf = (unsigned short*)(ws + 0);            // after K1
  unsigned short* hs_bf = (unsigned short*)(ws + 33554432ull);
  uint4* wpd = (uint4*)(ws + 35520512ull);                       // after K1
  uint4* wpe = (uint4*)(ws + 39714816ull);                       // after K1
  float* xg4 = (float*)(ws + 41943040ull);                       // dead after enc
  float* encpart = (float*)(ws + 41943040ull);                   // after enc
  float* eg4 = (float*)(ws + 52428800ull);                       // after enc
  unsigned short* aemb = (unsigned short*)(ws + 68157440ull);    // after enc
  unsigned short* ewih_bf = (unsigned short*)(ws + 83886080ull);
  float* encf = (float*)(ws + 100663296ull);
  unsigned short* encbf = (unsigned short*)(ws + 111149056ull);
  unsigned short* attnw_bf = (unsigned short*)(ws + 116391936ull);
  unsigned short* dwih_bf = (unsigned short*)(ws + 117440512ull);
  uint4* wat2 = (uint4*)(ws + 121634816ull);                     // 524,288 B
  float* cfin = (float*)(ws + 122159104ull);
  int* flag = (int*)(ws + 122290176ull);

  auto cvt = [&](const float* in, unsigned short* out, long n) {
    long n4 = n / 4;
    int blocks = (int)((n4 + 255) / 256);
    if (blocks > 2048) blocks = 2048;
    k_cvt<<<blocks, 256, 0, stream>>>(in, out, n4);
  };
  cvt(video, vid_bf, 5120L * 4096);
  cvt(eWih, ewih_bf, 2048L * 4096);
  cvt(attnW, attnw_bf, 512L * 1024);
  cvt(dWih, dwih_bf, 2048L * 1024);
  k_detect_i64<<<1, 256, 0, stream>>>(captions, flag);

  // K1: X_gates = video @ enc_Wih^T + ebih + ebhh  -> gate-packed [r][j][4]
  k_gemm<2><<<dim3(16, 40), 256, 0, stream>>>(vid_bf, 4096, ewih_bf, 4096, xg4, 2048, 4096, ebih, ebhh);
  cvt(fcW, fcw_bf, 32000L * 512);

  // f16 weight packs (write into vid_bf's old region -> must follow K1)
  k_pack_enc<<<512, 256, 0, stream>>>(eWhh, wpe);
  k_pack_dec<<<1024, 256, 0, stream>>>(dWih, dWhh, wpd);
  k_pack_attn2<<<128, 256, 0, stream>>>(attnW, wat2);

  k_enc3<<<64, 1024, 0, stream>>>((const float4*)xg4, wpe, encf, encbf, cfin);

  k_gather_emb<<<1920, 256, 0, stream>>>(emb, captions, flag, aemb);
  // EncPart = enc_out @ attn_W[:,512:]^T + attn_b   [5120 x 512]
  k_gemm<0><<<dim3(4, 40), 256, 0, stream>>>(encbf, 512, attnw_bf + 512, 1024, encpart, 512, 512, attnb, nullptr);
  // E_gates = emb[tok] @ dec_Wih[:,:512]^T + dbih + dbhh -> gate-packed [r][j][4]
  k_gemm<2><<<dim3(16, 15), 256, 0, stream>>>(aemb, 512, dwih_bf, 1024, eg4, 2048, 512, dbih, dbhh);

  k_dec3<<<64, 1024, 0, stream>>>(wpd, wat2, vw, (const float4*)eg4, encpart, encf, cfin, hs_bf);

  // FC: out[b][l][v] = Hs @ fc_W^T + fc_b   [1920 x 32000]
  k_gemm<1><<<dim3(250, 15), 256, 0, stream>>>(hs_bf, 512, fcw_bf, 512, (float*)d_out, 32000, 512, fcb, nullptr);
}

// Round 7
// 1389.053 us; speedup vs baseline: 8.2573x; 2.2808x over previous
//
#include <hip/hip_runtime.h>

// S2VT + attention — R7: 4-block teams per batch element.
//  R6 lesson: bottleneck = per-CU L2 BW (~135 GB/s) x only 64 CUs used.
//  R7: 256 blocks (all CUs). Team of 4 blocks per batch element; member m
//  owns hidden-unit slice [128m,128m+128). Weight traffic per CU drops 4x and
//  slices become L2-resident per XCD. Tiny per-step exchanges (h, hW, scores,
//  ctx partials) via write-through agent atomics + 4-member padded-flag syncs
//  (no fences, no RMW contention, teams co-resident at 1 block/CU).
//  h double-buffered across steps to avoid member-drift races.

#define DEV __device__ __forceinline__

typedef __attribute__((ext_vector_type(4))) float f32x4;
typedef __attribute__((ext_vector_type(8))) short bf16x8;
typedef _Float16 half2_t __attribute__((ext_vector_type(2)));

static constexpr int B_ = 64, T_ = 80, H_ = 512, L_ = 31, NDEC = 30;

DEV unsigned short f2bf(float f) {
  unsigned u = __builtin_bit_cast(unsigned, f);
  u += 0x7FFF + ((u >> 16) & 1);
  return (unsigned short)(u >> 16);
}
DEV float bf2f(unsigned short s) {
  unsigned u = (unsigned)s << 16;
  return __builtin_bit_cast(float, u);
}
DEV unsigned short f2h(float x) { return __builtin_bit_cast(unsigned short, (_Float16)x); }
DEV float h2f(unsigned short h) { return (float)__builtin_bit_cast(_Float16, h); }
DEV unsigned f2h2(float lo, float hi) { return (unsigned)f2h(lo) | ((unsigned)f2h(hi) << 16); }
DEV float fdot2(unsigned x, unsigned w, float acc) {
  return __builtin_amdgcn_fdot2(__builtin_bit_cast(half2_t, x),
                                __builtin_bit_cast(half2_t, w), acc, false);
}
DEV float4 acc8(float4 a, uint4 hv, uint4 w0, uint4 w1, uint4 w2, uint4 w3) {
  a.x = fdot2(hv.x, w0.x, a.x); a.y = fdot2(hv.x, w0.y, a.y);
  a.z = fdot2(hv.x, w0.z, a.z); a.w = fdot2(hv.x, w0.w, a.w);
  a.x = fdot2(hv.y, w1.x, a.x); a.y = fdot2(hv.y, w1.y, a.y);
  a.z = fdot2(hv.y, w1.z, a.z); a.w = fdot2(hv.y, w1.w, a.w);
  a.x = fdot2(hv.z, w2.x, a.x); a.y = fdot2(hv.z, w2.y, a.y);
  a.z = fdot2(hv.z, w2.z, a.z); a.w = fdot2(hv.z, w2.w, a.w);
  a.x = fdot2(hv.w, w3.x, a.x); a.y = fdot2(hv.w, w3.y, a.y);
  a.z = fdot2(hv.w, w3.z, a.z); a.w = fdot2(hv.w, w3.w, a.w);
  return a;
}
DEV float accS(float s, uint4 hv, uint4 w) {
  s = fdot2(hv.x, w.x, s); s = fdot2(hv.y, w.y, s);
  s = fdot2(hv.z, w.z, s); s = fdot2(hv.w, w.w, s);
  return s;
}
DEV float sigmoidf(float x) { return 1.f / (1.f + __expf(-x)); }
DEV float tanh_fast(float x) { float e = __expf(2.f * x); return (e - 1.f) / (e + 1.f); }

// write-through agent-visible stores / coherent loads
DEV void astf(float* p, float v) { __hip_atomic_store(p, v, __ATOMIC_RELAXED, __HIP_MEMORY_SCOPE_AGENT); }
DEV void astu(unsigned* p, unsigned v) { __hip_atomic_store(p, v, __ATOMIC_RELAXED, __HIP_MEMORY_SCOPE_AGENT); }
DEV void asti(int* p, int v) { __hip_atomic_store(p, v, __ATOMIC_RELAXED, __HIP_MEMORY_SCOPE_AGENT); }
DEV float aldf(const float* p) { return __hip_atomic_load((float*)p, __ATOMIC_RELAXED, __HIP_MEMORY_SCOPE_AGENT); }
DEV unsigned aldu(const unsigned* p) { return __hip_atomic_load((unsigned*)p, __ATOMIC_RELAXED, __HIP_MEMORY_SCOPE_AGENT); }
DEV int aldi(const int* p) { return __hip_atomic_load((int*)p, __ATOMIC_RELAXED, __HIP_MEMORY_SCOPE_AGENT); }

// 4-member team sync: member m stores its padded flag line; all poll 4 lines.
// Entry __syncthreads drains vmcnt (write-through stores visible) -> release.
DEV void tsync(int* tf, int m, int ph) {
  __syncthreads();
  if (threadIdx.x == 0) asti(tf + m * 16, ph);
  if (threadIdx.x < 4)
    while (aldi(tf + (int)threadIdx.x * 16) < ph) __builtin_amdgcn_s_sleep(1);
  __syncthreads();
}

// ---------------- fp32 -> bf16 convert ----------------
__global__ __launch_bounds__(256) void k_cvt(const float* __restrict__ in,
                                             unsigned short* __restrict__ out, long n4) {
  long i = (long)blockIdx.x * 256 + threadIdx.x;
  long stride = (long)gridDim.x * 256;
  for (; i < n4; i += stride) {
    float4 v = reinterpret_cast<const float4*>(in)[i];
    ushort4 o;
    o.x = f2bf(v.x); o.y = f2bf(v.y); o.z = f2bf(v.z); o.w = f2bf(v.w);
    reinterpret_cast<ushort4*>(out)[i] = o;
  }
}

// ---------------- int64-vs-int32 caption detect ----------------
__global__ void k_detect_i64(const int* __restrict__ cap, int* __restrict__ flag) {
  __shared__ int s;
  if (threadIdx.x == 0) s = 0;
  __syncthreads();
  int acc = 0;
  for (int i = threadIdx.x; i < (B_ * L_) / 2; i += 256) acc |= cap[2 * i + 1];
  if (acc) atomicOr(&s, 1);
  __syncthreads();
  if (threadIdx.x == 0) flag[0] = (s == 0) ? 1 : 0;
}

// ---------------- embedding gather (rows r = l*64+b) ----------------
__global__ __launch_bounds__(256) void k_gather_emb(const float* __restrict__ emb,
                                                    const int* __restrict__ cap,
                                                    const int* __restrict__ flag,
                                                    unsigned short* __restrict__ aemb) {
  int r = blockIdx.x;
  int l = r >> 6, b = r & 63;
  int ci = b * L_ + l;
  int tok = flag[0] ? cap[2 * ci] : cap[ci];
  const float* src = emb + (size_t)tok * H_;
  unsigned short* dst = aemb + (size_t)r * H_;
  for (int c = threadIdx.x; c < H_; c += 256) dst[c] = f2bf(src[c]);
}

// ---------------- f16 weight pack kernels (one-time) ----------------
__global__ __launch_bounds__(256) void k_pack_enc(const float* __restrict__ whh,
                                                  uint4* __restrict__ wpe) {
  int idx = blockIdx.x * 256 + threadIdx.x;  // k2(256) x j(512)
  int k2 = idx >> 9, j = idx & 511;
  float2 r0 = *(const float2*)(whh + (size_t)(j) * 512 + 2 * k2);
  float2 r1 = *(const float2*)(whh + (size_t)(512 + j) * 512 + 2 * k2);
  float2 r2 = *(const float2*)(whh + (size_t)(1024 + j) * 512 + 2 * k2);
  float2 r3 = *(const float2*)(whh + (size_t)(1536 + j) * 512 + 2 * k2);
  wpe[idx] = make_uint4(f2h2(r0.x, r0.y), f2h2(r1.x, r1.y), f2h2(r2.x, r2.y), f2h2(r3.x, r3.y));
}

__global__ __launch_bounds__(256) void k_pack_dec(const float* __restrict__ dwih,
                                                  const float* __restrict__ dwhh,
                                                  uint4* __restrict__ wpd) {
  int idx = blockIdx.x * 256 + threadIdx.x;  // k2(512) x j(512)
  int k2 = idx >> 9, j = idx & 511;
  float2 r[4];
  if (k2 < 256) {
#pragma unroll
    for (int g = 0; g < 4; ++g)
      r[g] = *(const float2*)(dwih + (size_t)(g * 512 + j) * 1024 + 512 + 2 * k2);
  } else {
#pragma unroll
    for (int g = 0; g < 4; ++g)
      r[g] = *(const float2*)(dwhh + (size_t)(g * 512 + j) * 512 + 2 * (k2 - 256));
  }
  wpd[idx] = make_uint4(f2h2(r[0].x, r[0].y), f2h2(r[1].x, r[1].y),
                        f2h2(r[2].x, r[2].y), f2h2(r[3].x, r[3].y));
}

__global__ __launch_bounds__(256) void k_pack_attn2(const float* __restrict__ attnw,
                                                    uint4* __restrict__ wat2) {
  int idx = blockIdx.x * 256 + threadIdx.x;  // k8(64) x u(512)
  int k8 = idx >> 9, u = idx & 511;
  const float* p = attnw + (size_t)u * 1024 + 8 * k8;
  wat2[idx] = make_uint4(f2h2(p[0], p[1]), f2h2(p[2], p[3]),
                         f2h2(p[4], p[5]), f2h2(p[6], p[7]));
}

// ---------------- bf16 MFMA GEMM: C[M,N] = A[M,K] * B[N,K]^T + bias ----------------
// OUT_MODE 0: row-major; 1: FC row remap; 2: gate-packed [row][j][4]
template <int OUT_MODE>
__global__ __launch_bounds__(256) void k_gemm(const unsigned short* __restrict__ A, int lda,
                                              const unsigned short* __restrict__ Bm, int ldb,
                                              float* __restrict__ C, int N, int K,
                                              const float* __restrict__ bias0,
                                              const float* __restrict__ bias1) {
  __shared__ __align__(16) unsigned short As[128 * 40];
  __shared__ __align__(16) unsigned short Bs[128 * 40];
  const int tid = threadIdx.x;
  const int m0 = blockIdx.y * 128, n0 = blockIdx.x * 128;
  const int wave = tid >> 6, lane = tid & 63;
  const int wm = wave >> 1, wn = wave & 1;
  const int lr = lane & 15, lk = lane >> 4;

  f32x4 acc[4][4];
#pragma unroll
  for (int m = 0; m < 4; ++m)
#pragma unroll
    for (int n = 0; n < 4; ++n) acc[m][n] = (f32x4){0.f, 0.f, 0.f, 0.f};

  const int c0 = tid, c1 = tid + 256;
  const int ar0 = c0 >> 2, as0 = c0 & 3;
  const int ar1 = c1 >> 2, as1 = c1 & 3;

  for (int k0 = 0; k0 < K; k0 += 32) {
    uint4 va0 = *(const uint4*)(A + (size_t)(m0 + ar0) * lda + k0 + as0 * 8);
    uint4 va1 = *(const uint4*)(A + (size_t)(m0 + ar1) * lda + k0 + as1 * 8);
    uint4 vb0 = *(const uint4*)(Bm + (size_t)(n0 + ar0) * ldb + k0 + as0 * 8);
    uint4 vb1 = *(const uint4*)(Bm + (size_t)(n0 + ar1) * ldb + k0 + as1 * 8);
    *(uint4*)(As + ar0 * 40 + as0 * 8) = va0;
    *(uint4*)(As + ar1 * 40 + as1 * 8) = va1;
    *(uint4*)(Bs + ar0 * 40 + as0 * 8) = vb0;
    *(uint4*)(Bs + ar1 * 40 + as1 * 8) = vb1;
    __syncthreads();
    bf16x8 af[4], bfr[4];
#pragma unroll
    for (int m = 0; m < 4; ++m)
      af[m] = *(const bf16x8*)(As + (wm * 64 + m * 16 + lr) * 40 + lk * 8);
#pragma unroll
    for (int n = 0; n < 4; ++n)
      bfr[n] = *(const bf16x8*)(Bs + (wn * 64 + n * 16 + lr) * 40 + lk * 8);
#pragma unroll
    for (int m = 0; m < 4; ++m)
#pragma unroll
      for (int n = 0; n < 4; ++n)
        acc[m][n] = __builtin_amdgcn_mfma_f32_16x16x32_bf16(af[m], bfr[n], acc[m][n], 0, 0, 0);
    __syncthreads();
  }
#pragma unroll
  for (int m = 0; m < 4; ++m) {
#pragma unroll
    for (int n = 0; n < 4; ++n) {
      const int col = n0 + wn * 64 + n * 16 + lr;
      float bv = (bias0 ? bias0[col] : 0.f) + (bias1 ? bias1[col] : 0.f);
#pragma unroll
      for (int j = 0; j < 4; ++j) {
        const int row = m0 + wm * 64 + m * 16 + lk * 4 + j;
        float v = acc[m][n][j] + bv;
        if (OUT_MODE == 0) {
          C[(size_t)row * N + col] = v;
        } else if (OUT_MODE == 1) {
          int l = row >> 6, b = row & 63;
          C[((size_t)b * NDEC + l) * (size_t)N + col] = v;
        } else {
          C[((size_t)row * 512 + (col & 511)) * 4 + (col >> 9)] = v;
        }
      }
    }
  }
}

// ---------------- encoder: team of 4 blocks per batch; member m owns j-slice ----------------
__global__ __launch_bounds__(1024) void k_enc4(const float4* __restrict__ xg4,
                                               const uint4* __restrict__ wpe,
                                               float* __restrict__ encf,
                                               unsigned short* __restrict__ encbf,
                                               float* __restrict__ cfin,
                                               unsigned* __restrict__ h16E,  // [2][64][256]
                                               int* __restrict__ flagsE) {
  __shared__ __align__(16) unsigned short h16[512];
  __shared__ __align__(16) float psum[8 * 4 * 128];
  __shared__ unsigned short hnew[128];
  const int bid = blockIdx.x, b = bid >> 2, m = bid & 3, tid = threadIdx.x;
  const int j128 = tid & 127, ks = tid >> 7;
  const int j = m * 128 + j128;
  int* tf = flagsE + b * 64;
  float c = 0.f;
  if (tid < 256) ((unsigned*)h16)[tid] = 0u;
  __syncthreads();
  const uint4* hp4 = (const uint4*)h16;
  for (int t = 0; t < T_; ++t) {
    float4 a = {0.f, 0.f, 0.f, 0.f}, a1 = a;
#pragma unroll 2
    for (int k8 = ks * 8; k8 < ks * 8 + 8; k8 += 2) {
      uint4 h0 = hp4[k8], h1 = hp4[k8 + 1];
      a = acc8(a, h0, wpe[((k8 * 4 + 0) << 9) | j], wpe[((k8 * 4 + 1) << 9) | j],
               wpe[((k8 * 4 + 2) << 9) | j], wpe[((k8 * 4 + 3) << 9) | j]);
      a1 = acc8(a1, h1, wpe[((k8 * 4 + 4) << 9) | j], wpe[((k8 * 4 + 5) << 9) | j],
                wpe[((k8 * 4 + 6) << 9) | j], wpe[((k8 * 4 + 7) << 9) | j]);
    }
    psum[ks * 512 + 0 * 128 + j128] = a.x + a1.x;
    psum[ks * 512 + 1 * 128 + j128] = a.y + a1.y;
    psum[ks * 512 + 2 * 128 + j128] = a.z + a1.z;
    psum[ks * 512 + 3 * 128 + j128] = a.w + a1.w;
    __syncthreads();
    if (tid < 128) {
      float4 xa = xg4[((size_t)b * T_ + t) * 512 + m * 128 + tid];
      float g0 = xa.x, g1 = xa.y, g2 = xa.z, g3 = xa.w;
#pragma unroll
      for (int q = 0; q < 8; ++q) {
        g0 += psum[q * 512 + 0 * 128 + tid];
        g1 += psum[q * 512 + 1 * 128 + tid];
        g2 += psum[q * 512 + 2 * 128 + tid];
        g3 += psum[q * 512 + 3 * 128 + tid];
      }
      c = sigmoidf(g1) * c + sigmoidf(g0) * tanh_fast(g2);
      float h = sigmoidf(g3) * tanh_fast(c);
      size_t o = ((size_t)b * T_ + t) * 512 + m * 128 + tid;
      encf[o] = h;
      encbf[o] = f2bf(h);
      hnew[tid] = f2h(h);
      if (t == T_ - 1) cfin[b * 512 + m * 128 + tid] = c;
    }
    __syncthreads();
    const int p = t & 1;
    if (tid < 64)
      astu(h16E + (size_t)p * 64 * 256 + b * 256 + m * 64 + tid,
           (unsigned)hnew[2 * tid] | ((unsigned)hnew[2 * tid + 1] << 16));
    tsync(tf, m, t + 1);
    if (t < T_ - 1) {
      if (tid < 256)
        ((unsigned*)h16)[tid] = aldu(h16E + (size_t)p * 64 * 256 + b * 256 + tid);
      __syncthreads();
    }
  }
}

// ---------------- decoder: team of 4 blocks per batch; 4 syncs/step ----------------
__global__ __launch_bounds__(1024) void k_dec4(const uint4* __restrict__ wpd,
                                               const uint4* __restrict__ wat2,
                                               const float* __restrict__ vw,
                                               const float4* __restrict__ eg4,
                                               const float* __restrict__ encpart,
                                               const unsigned short* __restrict__ encbf,
                                               const float* __restrict__ encf,
                                               const float* __restrict__ cfin,
                                               unsigned short* __restrict__ hsbf,
                                               float* __restrict__ hwbuf,     // [64][512]
                                               float* __restrict__ scbuf,     // [64][80]
                                               unsigned* __restrict__ ctxpH,  // [64][4][256]
                                               unsigned* __restrict__ h16D,   // [2][64][256]
                                               int* __restrict__ flagsD) {
  __shared__ __align__(16) unsigned short xv16[1024];  // [ctx f16; h f16]
  __shared__ float hw[512];
  __shared__ float vsm[512];
  __shared__ float sc[80], wts[80];
  __shared__ __align__(16) float psum1[8 * 128];
  __shared__ __align__(16) float psum[8 * 4 * 128];
  __shared__ __align__(16) float4 ctxp[8 * 128];
  __shared__ unsigned short hnew[128];
  const int bid = blockIdx.x, b = bid >> 2, m = bid & 3, tid = threadIdx.x;
  int* tf = flagsD + b * 64;
  if (tid < 512) {
    vsm[tid] = vw[tid];
    xv16[512 + tid] = f2h(encf[((size_t)b * T_ + T_ - 1) * 512 + tid]);
  }
  float c = 0.f;
  if (tid < 128) c = cfin[b * 512 + m * 128 + tid];
  __syncthreads();
  const uint4* xp4 = (const uint4*)xv16;
  const uint4* xh4 = xp4 + 64;

  for (int l = 0; l < NDEC; ++l) {
    // phase 1: hW partials (u-slice, k-split)
    {
      const int u128 = tid & 127, ks = tid >> 7;
      const int u = m * 128 + u128;
      float s = 0.f, s1 = 0.f;
#pragma unroll 2
      for (int k8 = ks * 8; k8 < ks * 8 + 8; k8 += 2) {
        s = accS(s, xh4[k8], wat2[(k8 << 9) | u]);
        s1 = accS(s1, xh4[k8 + 1], wat2[((k8 + 1) << 9) | u]);
      }
      psum1[ks * 128 + u128] = s + s1;
    }
    __syncthreads();
    if (tid < 128) {
      float s = 0.f;
#pragma unroll
      for (int q = 0; q < 8; ++q) s += psum1[q * 128 + tid];
      astf(hwbuf + b * 512 + m * 128 + tid, s);
    }
    tsync(tf, m, 4 * l + 1);
    if (tid < 512) hw[tid] = aldf(hwbuf + b * 512 + tid);
    __syncthreads();
    // phase 2a: scores slice t in [20m, 20m+20)
    {
      const int wv = tid >> 6, ln = tid & 63;
      for (int tt = wv; tt < 20; tt += 16) {
        const int t = m * 20 + tt;
        const float* ep = encpart + ((size_t)b * T_ + t) * 512;
        float p = 0.f;
#pragma unroll
        for (int q = 0; q < 8; ++q) {
          int u = ln + q * 64;
          p += vsm[u] * tanh_fast(hw[u] + ep[u]);
        }
#pragma unroll
        for (int s = 1; s < 64; s <<= 1) p += __shfl_xor(p, s, 64);
        if (ln == 0) astf(scbuf + b * 80 + t, p);
      }
    }
    tsync(tf, m, 4 * l + 2);
    if (tid < 80) sc[tid] = aldf(scbuf + b * 80 + tid);
    __syncthreads();
    // phase 2b: softmax (redundant, wave 0)
    if (tid < 64) {
      float x0 = sc[tid];
      float x1 = (tid < 16) ? sc[64 + tid] : -1e30f;
      float mx = fmaxf(x0, x1);
#pragma unroll
      for (int s = 1; s < 64; s <<= 1) mx = fmaxf(mx, __shfl_xor(mx, s, 64));
      float e0 = __expf(x0 - mx);
      float e1 = (tid < 16) ? __expf(x1 - mx) : 0.f;
      float sm = e0 + e1;
#pragma unroll
      for (int s = 1; s < 64; s <<= 1) sm += __shfl_xor(sm, s, 64);
      wts[tid] = e0 / sm;
      if (tid < 16) wts[64 + tid] = e1 / sm;
    }
    __syncthreads();
    // phase 2c: ctx partial over own t-slice (reads bf16 enc_out)
    {
      const int tsub = tid >> 7, j4 = tid & 127;
      float4 acc = {0.f, 0.f, 0.f, 0.f};
      for (int tl = tsub; tl < 20; tl += 8) {
        const int t = m * 20 + tl;
        float w = wts[t];
        ushort4 e = *(const ushort4*)(encbf + ((size_t)b * T_ + t) * 512 + j4 * 4);
        acc.x += w * bf2f(e.x); acc.y += w * bf2f(e.y);
        acc.z += w * bf2f(e.z); acc.w += w * bf2f(e.w);
      }
      ctxp[tsub * 128 + j4] = acc;
    }
    __syncthreads();
    if (tid < 256) {
      const float* cp = (const float*)ctxp;
      float s0 = 0.f, s1 = 0.f;
#pragma unroll
      for (int q = 0; q < 8; ++q) {
        s0 += cp[q * 512 + 2 * tid];
        s1 += cp[q * 512 + 2 * tid + 1];
      }
      astu(ctxpH + ((size_t)b * 4 + m) * 256 + tid, f2h2(s0, s1));
    }
    tsync(tf, m, 4 * l + 3);
    if (tid < 256) {
      float s0 = 0.f, s1 = 0.f;
#pragma unroll
      for (int mm = 0; mm < 4; ++mm) {
        unsigned u = aldu(ctxpH + ((size_t)b * 4 + mm) * 256 + tid);
        s0 += h2f((unsigned short)(u & 0xffffu));
        s1 += h2f((unsigned short)(u >> 16));
      }
      ((unsigned*)xv16)[tid] = f2h2(s0, s1);
    }
    __syncthreads();
    // phase 3: gates (j-slice, k-split over [ctx; h])
    {
      const int j128 = tid & 127, ks = tid >> 7;
      const int j = m * 128 + j128;
      float4 a = {0.f, 0.f, 0.f, 0.f}, a1 = a;
#pragma unroll 2
      for (int k8 = ks * 16; k8 < ks * 16 + 16; k8 += 2) {
        uint4 h0 = xp4[k8], h1 = xp4[k8 + 1];
        a = acc8(a, h0, wpd[((k8 * 4 + 0) << 9) | j], wpd[((k8 * 4 + 1) << 9) | j],
                 wpd[((k8 * 4 + 2) << 9) | j], wpd[((k8 * 4 + 3) << 9) | j]);
        a1 = acc8(a1, h1, wpd[((k8 * 4 + 4) << 9) | j], wpd[((k8 * 4 + 5) << 9) | j],
                  wpd[((k8 * 4 + 6) << 9) | j], wpd[((k8 * 4 + 7) << 9) | j]);
      }
      psum[ks * 512 + 0 * 128 + j128] = a.x + a1.x;
      psum[ks * 512 + 1 * 128 + j128] = a.y + a1.y;
      psum[ks * 512 + 2 * 128 + j128] = a.z + a1.z;
      psum[ks * 512 + 3 * 128 + j128] = a.w + a1.w;
    }
    __syncthreads();
    if (tid < 128) {
      float4 xa = eg4[((size_t)l * 64 + b) * 512 + m * 128 + tid];
      float g0 = xa.x, g1 = xa.y, g2 = xa.z, g3 = xa.w;
#pragma unroll
      for (int q = 0; q < 8; ++q) {
        g0 += psum[q * 512 + 0 * 128 + tid];
        g1 += psum[q * 512 + 1 * 128 + tid];
        g2 += psum[q * 512 + 2 * 128 + tid];
        g3 += psum[q * 512 + 3 * 128 + tid];
      }
      c = sigmoidf(g1) * c + sigmoidf(g0) * tanh_fast(g2);
      float h = sigmoidf(g3) * tanh_fast(c);
      hsbf[((size_t)l * 64 + b) * 512 + m * 128 + tid] = f2bf(h);
      hnew[tid] = f2h(h);
    }
    __syncthreads();
    const int p = l & 1;
    if (tid < 64)
      astu(h16D + (size_t)p * 64 * 256 + b * 256 + m * 64 + tid,
           (unsigned)hnew[2 * tid] | ((unsigned)hnew[2 * tid + 1] << 16));
    tsync(tf, m, 4 * l + 4);
    if (l < NDEC - 1) {
      if (tid < 256)
        ((unsigned*)xv16)[256 + tid] = aldu(h16D + (size_t)p * 64 * 256 + b * 256 + tid);
      __syncthreads();
    }
  }
}

// ---------------- launch ----------------
extern "C" void kernel_launch(void* const* d_in, const int* in_sizes, int n_in,
                              void* d_out, int out_size, void* d_ws, size_t ws_size,
                              hipStream_t stream) {
  const float* video = (const float*)d_in[0];
  const int* captions = (const int*)d_in[1];
  const float* emb = (const float*)d_in[2];
  const float* eWih = (const float*)d_in[3];
  const float* eWhh = (const float*)d_in[4];
  const float* ebih = (const float*)d_in[5];
  const float* ebhh = (const float*)d_in[6];
  const float* attnW = (const float*)d_in[7];
  const float* attnb = (const float*)d_in[8];
  const float* vw = (const float*)d_in[9];
  const float* dWih = (const float*)d_in[10];
  const float* dWhh = (const float*)d_in[11];
  const float* dbih = (const float*)d_in[12];
  const float* dbhh = (const float*)d_in[13];
  const float* fcW = (const float*)d_in[14];
  const float* fcb = (const float*)d_in[15];

  char* ws = (char*)d_ws;
  unsigned short* vid_bf = (unsigned short*)(ws + 0);            // dead after K1
  unsigned short* fcw_bf = (unsigned short*)(ws + 0);            // [0, 32,768,000) after K1
  // team-exchange buffers live in the gap [32,768,000 .. 33,554,432) (post-K1 only)
  const size_t G = 32768000ull;
  unsigned* h16E = (unsigned*)(ws + G + 0);            // 131,072
  unsigned* h16D = (unsigned*)(ws + G + 131072);       // 131,072
  float* hwbufD = (float*)(ws + G + 262144);           // 131,072
  float* scbufD = (float*)(ws + G + 393216);           // 20,480
  unsigned* ctxpH = (unsigned*)(ws + G + 413696);      // 262,144
  int* flagsE = (int*)(ws + G + 675840);               // 16,384
  int* flagsD = (int*)(ws + G + 692224);               // 16,384  (end 708,608 < 786,432)
  unsigned short* hs_bf = (unsigned short*)(ws + 33554432ull);
  uint4* wpd = (uint4*)(ws + 35520512ull);                       // after K1
  uint4* wpe = (uint4*)(ws + 39714816ull);                       // after K1
  float* xg4 = (float*)(ws + 41943040ull);                       // dead after enc
  float* encpart = (float*)(ws + 41943040ull);                   // after enc
  float* eg4 = (float*)(ws + 52428800ull);                       // after enc
  unsigned short* aemb = (unsigned short*)(ws + 68157440ull);    // after enc
  unsigned short* ewih_bf = (unsigned short*)(ws + 83886080ull);
  float* encf = (float*)(ws + 100663296ull);
  unsigned short* encbf = (unsigned short*)(ws + 111149056ull);
  unsigned short* attnw_bf = (unsigned short*)(ws + 116391936ull);
  unsigned short* dwih_bf = (unsigned short*)(ws + 117440512ull);
  uint4* wat2 = (uint4*)(ws + 121634816ull);
  float* cfin = (float*)(ws + 122159104ull);
  int* flag = (int*)(ws + 122290176ull);

  auto cvt = [&](const float* in, unsigned short* out, long n) {
    long n4 = n / 4;
    int blocks = (int)((n4 + 255) / 256);
    if (blocks > 2048) blocks = 2048;
    k_cvt<<<blocks, 256, 0, stream>>>(in, out, n4);
  };
  cvt(video, vid_bf, 5120L * 4096);
  cvt(eWih, ewih_bf, 2048L * 4096);
  cvt(attnW, attnw_bf, 512L * 1024);
  cvt(dWih, dwih_bf, 2048L * 1024);
  k_detect_i64<<<1, 256, 0, stream>>>(captions, flag);

  // K1: X_gates = video @ enc_Wih^T + ebih + ebhh  -> gate-packed [r][j][4]
  k_gemm<2><<<dim3(16, 40), 256, 0, stream>>>(vid_bf, 4096, ewih_bf, 4096, xg4, 2048, 4096, ebih, ebhh);
  cvt(fcW, fcw_bf, 32000L * 512);

  // f16 weight packs (overlap vid_bf's old region -> must follow K1)
  k_pack_enc<<<512, 256, 0, stream>>>(eWhh, wpe);
  k_pack_dec<<<1024, 256, 0, stream>>>(dWih, dWhh, wpd);
  k_pack_attn2<<<128, 256, 0, stream>>>(attnW, wat2);

  // zero team-sync flags (gap region is clobbered by cvt(video) -> zero AFTER K1)
  hipMemsetAsync(ws + G + 675840, 0, 32768, stream);

  k_enc4<<<256, 1024, 0, stream>>>((const float4*)xg4, wpe, encf, encbf, cfin, h16E, flagsE);

  k_gather_emb<<<1920, 256, 0, stream>>>(emb, captions, flag, aemb);
  // EncPart = enc_out @ attn_W[:,512:]^T + attn_b   [5120 x 512]
  k_gemm<0><<<dim3(4, 40), 256, 0, stream>>>(encbf, 512, attnw_bf + 512, 1024, encpart, 512, 512, attnb, nullptr);
  // E_gates = emb[tok] @ dec_Wih[:,:512]^T + dbih + dbhh -> gate-packed [r][j][4]
  k_gemm<2><<<dim3(16, 15), 256, 0, stream>>>(aemb, 512, dwih_bf, 1024, eg4, 2048, 512, dbih, dbhh);

  k_dec4<<<256, 1024, 0, stream>>>(wpd, wat2, vw, (const float4*)eg4, encpart, encbf, encf,
                                   cfin, hs_bf, hwbufD, scbufD, ctxpH, h16D, flagsD);

  // FC: out[b][l][v] = Hs @ fc_W^T + fc_b   [1920 x 32000]
  k_gemm<1><<<dim3(250, 15), 256, 0, stream>>>(hs_bf, 512, fcw_bf, 512, (float*)d_out, 32000, 512, fcb, nullptr);
}